// Round 2
// baseline (542.507 us; speedup 1.0000x reference)
//
#include <hip/hip_runtime.h>
#include <math.h>

#define NN 50000
#define EE 800000
#define RR 8
#define SLOPE 0.2f
#define SEGS (NN * RR)            /* 400000 per-(node,relation) segments */
#define NBLK ((SEGS + 255) / 256) /* 1563 scan blocks */

__device__ __forceinline__ float leaky(float v) { return v >= 0.f ? v : SLOPE * v; }

__device__ __forceinline__ void fmacc(float4& a, const float4& v, float p) {
    a.x = fmaf(v.x, p, a.x);
    a.y = fmaf(v.y, p, a.y);
    a.z = fmaf(v.z, p, a.z);
    a.w = fmaf(v.w, p, a.w);
}

__device__ __forceinline__ void red4(float4& a, int m) {
    a.x += __shfl_xor(a.x, m);
    a.y += __shfl_xor(a.y, m);
    a.z += __shfl_xor(a.z, m);
    a.w += __shfl_xor(a.w, m);
}

// ============================ CSR build ============================
__global__ void k_count2(const int* __restrict__ dst, const int* __restrict__ et,
                         int* __restrict__ cnt2) {
    int e = blockIdx.x * 256 + threadIdx.x;
    if (e < EE) atomicAdd(&cnt2[dst[e] * RR + et[e]], 1);
}

__global__ void k_scanA(const int* __restrict__ cnt2, int* __restrict__ rp,
                        int* __restrict__ bsum) {
    __shared__ int sh[256];
    int t = threadIdx.x;
    int i = blockIdx.x * 256 + t;
    int v = (i < SEGS) ? cnt2[i] : 0;
    sh[t] = v;
    __syncthreads();
    for (int off = 1; off < 256; off <<= 1) {
        int u = (t >= off) ? sh[t - off] : 0;
        __syncthreads();
        sh[t] += u;
        __syncthreads();
    }
    if (i < SEGS) rp[i] = sh[t] - v;
    if (t == 255) bsum[blockIdx.x] = sh[255];
}

__global__ void k_scanB(int* __restrict__ bsum) {
    __shared__ int sh[256];
    int t = threadIdx.x;
    int loc[8];
    int s = 0;
#pragma unroll
    for (int i = 0; i < 8; i++) {
        int idx = t * 8 + i;
        int v = (idx < NBLK) ? bsum[idx] : 0;
        loc[i] = v;
        s += v;
    }
    sh[t] = s;
    __syncthreads();
    for (int off = 1; off < 256; off <<= 1) {
        int u = (t >= off) ? sh[t - off] : 0;
        __syncthreads();
        sh[t] += u;
        __syncthreads();
    }
    int run = sh[t] - s;
#pragma unroll
    for (int i = 0; i < 8; i++) {
        int idx = t * 8 + i;
        if (idx < NBLK) {
            int v = loc[i];
            bsum[idx] = run;
            run += v;
        }
    }
}

__global__ void k_scanC(int* __restrict__ rp, const int* __restrict__ bsum,
                        int* __restrict__ wo) {
    int i = blockIdx.x * 256 + threadIdx.x;
    if (i < SEGS) {
        int v = rp[i] + bsum[blockIdx.x];
        rp[i] = v;
        wo[i] = v;
    }
    if (i == 0) rp[SEGS] = EE;
}

// fill packed keys: srcs2[pos] = src*8 + relation (single scattered store per edge)
__global__ void k_fill(const int* __restrict__ src, const int* __restrict__ dst,
                       const int* __restrict__ et, int* __restrict__ wo,
                       int* __restrict__ srcs2) {
    int e = blockIdx.x * 256 + threadIdx.x;
    if (e >= EE) return;
    int r = et[e];
    int seg = dst[e] * RR + r;
    int pos = atomicAdd(&wo[seg], 1);
    srcs2[pos] = (src[e] << 3) | r;
}

// ==== prep (merged): padded weights, logit projections, stacked Wb1, Wcat2e compose ====
__global__ void k_prep(const float* __restrict__ wg1, const float* __restrict__ wg2,
                       const float* __restrict__ root1, const float* __restrict__ root2,
                       const float* __restrict__ basis1, const float* __restrict__ basis2,
                       const float* __restrict__ comp2,
                       const float* __restrict__ asrc1, const float* __restrict__ adst1,
                       const float* __restrict__ asrc2, const float* __restrict__ adst2,
                       float* __restrict__ Wcat2e, float* __restrict__ wg1r,
                       float* __restrict__ Wstk, float* __restrict__ U1p,
                       float* __restrict__ U2p, float* __restrict__ Wb1) {
    int idx = blockIdx.x * 256 + threadIdx.x;
    if (idx < 16384) {  // wg1r[h][k][c] (c<32 valid)
        int h = idx >> 12, kc = idx & 4095;
        int k = kc >> 6, c = kc & 63;
        wg1r[idx] = (c < 32) ? wg1[k * 128 + h * 32 + c] : 0.f;
    } else if (idx < 24576) {  // Wstk[h*32+k][c] = wg2[k][h*16+c] (c<16 valid)
        int j = idx - 16384;
        int row = j >> 6, c = j & 63;
        int h = row >> 5, k = row & 31;
        Wstk[j] = (c < 16) ? wg2[k * 64 + h * 16 + c] : 0.f;
    } else if (idx < 32768) {  // Wcat2e root block: [128][col 0-63] = root2 zero-padded
        int j = idx - 24576;
        int k = j >> 6, c = j & 63;
        Wcat2e[k * 320 + c] = (c < 32) ? root2[k * 32 + c] : 0.f;
    } else if (idx < 36864) {  // U1p[k][j]: j<4 src head j, 4<=j<8 dst head j-4, else 0
        int j0 = idx - 32768;
        int k = j0 >> 6, j = j0 & 63;
        float s = 0.f;
        if (j < 8) {
            int h = j & 3;
            const float* a = (j < 4) ? asrc1 : adst1;
            for (int c = 0; c < 32; c++) s += wg1[k * 128 + h * 32 + c] * a[h * 32 + c];
        }
        U1p[j0] = s;
    } else if (idx < 38912) {  // U2p[k][j]
        int j0 = idx - 36864;
        int k = j0 >> 6, j = j0 & 63;
        float s = 0.f;
        if (j < 8) {
            int h = j & 3;
            const float* a = (j < 4) ? asrc2 : adst2;
            for (int c = 0; c < 16; c++) s += wg2[k * 64 + h * 16 + c] * a[h * 16 + c];
        }
        U2p[j0] = s;
    } else if (idx < 55296) {  // Wb1 rows 0-255 = basis1 [4][64][64] flat copy
        Wb1[idx - 38912] = basis1[idx - 38912];
    } else if (idx < 59392) {  // Wb1 rows 256-319 = root1
        Wb1[idx - 38912] = root1[idx - 55296];
    } else if (idx < 92160) {  // Wcat2e basis-composed block: [128][col 64-319]
        int j = idx - 59392;
        int i = j >> 8, rc = j & 255;
        int r = rc >> 5, o = rc & 31;
        float acc = 0.f;
#pragma unroll
        for (int b = 0; b < 4; b++) acc += comp2[r * 4 + b] * basis2[b * 4096 + i * 32 + o];
        Wcat2e[i * 320 + 64 + rc] = acc;
    }
}

// ===== L1 basis-space gather: U[n][b][64] = sum_edges comp[r,b]*inv_cnt*x[src]; U[n][4][64]=x[n] =====
__global__ __launch_bounds__(256) void k_gagg1(const int* __restrict__ rp,
                                               const int* __restrict__ srcs2,
                                               const float* __restrict__ comp,
                                               const float* __restrict__ X,
                                               float* __restrict__ U) {
    __shared__ float4 sh_w[4][8];
    int wid = threadIdx.x >> 6, lane = threadIdx.x & 63;
    int n = blockIdx.x * 4 + wid;
    int rpv = (lane <= 8) ? rp[n * RR + lane] : 0;
    int nxt = __shfl(rpv, (lane + 1) & 63);
    if (lane < 8) {
        float inv = 1.f / (float)((nxt - rpv) > 0 ? (nxt - rpv) : 1);
        float4 c = *(const float4*)(comp + lane * 4);
        sh_w[wid][lane] = make_float4(c.x * inv, c.y * inv, c.z * inv, c.w * inv);
    }
    int q = lane & 15;
    int beg = rp[n * RR], end = rp[n * RR + RR];
    float4 a0 = make_float4(0.f, 0.f, 0.f, 0.f);
    float4 a1 = a0, a2 = a0, a3 = a0;
    int k = beg + (lane >> 4);
    for (; k + 4 < end; k += 8) {
        int key0 = srcs2[k], key1 = srcs2[k + 4];
        float4 w0 = sh_w[wid][key0 & 7], w1 = sh_w[wid][key1 & 7];
        float4 v0 = *(const float4*)(X + (size_t)(key0 >> 3) * 64 + q * 4);
        float4 v1 = *(const float4*)(X + (size_t)(key1 >> 3) * 64 + q * 4);
        fmacc(a0, v0, w0.x);
        fmacc(a1, v0, w0.y);
        fmacc(a2, v0, w0.z);
        fmacc(a3, v0, w0.w);
        fmacc(a0, v1, w1.x);
        fmacc(a1, v1, w1.y);
        fmacc(a2, v1, w1.z);
        fmacc(a3, v1, w1.w);
    }
    if (k < end) {
        int key0 = srcs2[k];
        float4 w0 = sh_w[wid][key0 & 7];
        float4 v0 = *(const float4*)(X + (size_t)(key0 >> 3) * 64 + q * 4);
        fmacc(a0, v0, w0.x);
        fmacc(a1, v0, w0.y);
        fmacc(a2, v0, w0.z);
        fmacc(a3, v0, w0.w);
    }
    red4(a0, 16); red4(a0, 32);
    red4(a1, 16); red4(a1, 32);
    red4(a2, 16); red4(a2, 32);
    red4(a3, 16); red4(a3, 32);
    if (lane < 16) {
        float* un = U + (size_t)n * 320;
        *(float4*)(un + 0 * 64 + q * 4) = a0;
        *(float4*)(un + 1 * 64 + q * 4) = a1;
        *(float4*)(un + 2 * 64 + q * 4) = a2;
        *(float4*)(un + 3 * 64 + q * 4) = a3;
        *(float4*)(un + 256 + q * 4) = *(const float4*)(X + (size_t)n * 64 + q * 4);
    }
}

// ============ big tiled GEMM: 128 nodes x 64 cols; Kc=32 (26 KB LDS -> 6 blocks/CU) ============
// Xs transposed+swizzled; mbcnt>0 -> XCD-grouped 1-D grid. ACT: 0=none, 2=relu(x+bias).
template <int KTOT, int MV = 64, int ACT = 0>
__global__ __launch_bounds__(256) void k_gemm128(const float* __restrict__ X, int ldX, int xmb,
                                                 const float* __restrict__ B, int ldB, int bmb,
                                                 float* __restrict__ Y, int ldY, size_t ymb,
                                                 const float* __restrict__ bias, int biasmb,
                                                 int nt, int mbcnt) {
    constexpr int Kc = (KTOT < 32) ? KTOT : 32;
    constexpr int KQ = Kc / 4;
    __shared__ __align__(16) float Xs[Kc * 136];
    __shared__ __align__(16) float Ws[Kc * 68];
    const int tid = threadIdx.x;
    const int tn8 = (tid >> 4) * 8;
    const int tm4 = (tid & 15) * 4;
    int tile, mb;
    if (mbcnt) {
        int b = blockIdx.x;
        int xcd = b & 7, slot = b >> 3;
        tile = (slot / mbcnt) * 8 + xcd;
        mb = slot % mbcnt;
        if (tile >= nt) return;  // block-uniform early exit (before any barrier)
    } else {
        tile = blockIdx.x;
        mb = blockIdx.y;
    }
    const int n0 = tile * 128;
    const float* Bm = B + (size_t)mb * bmb;
    const float* Xm = X + (size_t)mb * xmb;

    float acc[8][4];
#pragma unroll
    for (int a = 0; a < 8; a++)
#pragma unroll
        for (int b = 0; b < 4; b++) acc[a][b] = 0.f;

    for (int kk = 0; kk < KTOT; kk += Kc) {
        if (kk) __syncthreads();
        for (int i = tid; i < 128 * KQ; i += 256) {
            int nl = i / KQ, kq = i % KQ;
            float4 v = make_float4(0.f, 0.f, 0.f, 0.f);
            if (n0 + nl < NN)
                v = *reinterpret_cast<const float4*>(Xm + (size_t)(n0 + nl) * ldX + kk + 4 * kq);
            int col = (nl + 4 * kq) & 127;
            Xs[(4 * kq + 0) * 136 + col] = v.x;
            Xs[(4 * kq + 1) * 136 + col] = v.y;
            Xs[(4 * kq + 2) * 136 + col] = v.z;
            Xs[(4 * kq + 3) * 136 + col] = v.w;
        }
        for (int i = tid; i < Kc * 16; i += 256) {
            int kl = i >> 4, cq = i & 15;
            float4 v = *reinterpret_cast<const float4*>(Bm + (size_t)(kk + kl) * ldB + 4 * cq);
            *reinterpret_cast<float4*>(&Ws[kl * 68 + 4 * cq]) = v;
        }
        __syncthreads();
#pragma unroll 4
        for (int k = 0; k < Kc; k++) {
            float4 xq0 = *reinterpret_cast<const float4*>(&Xs[k * 136 + ((tn8 + (k & ~3)) & 127)]);
            float4 xq1 = *reinterpret_cast<const float4*>(&Xs[k * 136 + ((tn8 + 4 + (k & ~3)) & 127)]);
            float4 wq = *reinterpret_cast<const float4*>(&Ws[k * 68 + tm4]);
            float xa[8] = {xq0.x, xq0.y, xq0.z, xq0.w, xq1.x, xq1.y, xq1.z, xq1.w};
            float wa[4] = {wq.x, wq.y, wq.z, wq.w};
#pragma unroll
            for (int a = 0; a < 8; a++)
#pragma unroll
                for (int b = 0; b < 4; b++) acc[a][b] += xa[a] * wa[b];
        }
    }
    if (MV == 64 || tm4 < MV) {
        float4 bv = make_float4(0.f, 0.f, 0.f, 0.f);
        if (bias) bv = *reinterpret_cast<const float4*>(bias + (size_t)mb * biasmb + tm4);
#pragma unroll
        for (int a = 0; a < 8; a++) {
            int n = n0 + tn8 + a;
            if (n < NN) {
                float4 v = make_float4(acc[a][0] + bv.x, acc[a][1] + bv.y,
                                       acc[a][2] + bv.z, acc[a][3] + bv.w);
                if (ACT == 2) {
                    v.x = fmaxf(v.x, 0.f);
                    v.y = fmaxf(v.y, 0.f);
                    v.z = fmaxf(v.z, 0.f);
                    v.w = fmaxf(v.w, 0.f);
                }
                *reinterpret_cast<float4*>(Y + (size_t)mb * ymb + (size_t)n * ldY + tm4) = v;
            }
        }
    }
}

// ===== layer-3 full transform: 128 nodes x 128 cols, 8x8/thread, split-half col mapping =====
// Thread owns cols {tm4..tm4+3} and {64+tm4..64+tm4+3}: both Ws reads are the proven
// conflict-free 16-lane x stride-4 pattern (132 = 4 mod 32, same bank math as stride 68).
// ct=0/1: relation panels (Wcat2e cols 64+ct*128..). ct=2: root panel (cols 0-63, zero-pad),
// writes only the first acc half. Y = P base; panel p at P + p*NN*64 (p=0 root/x3, 1-4 rel).
__global__ __launch_bounds__(256) void k_gemmL3(const float* __restrict__ X,
                                                const float* __restrict__ B,
                                                float* __restrict__ Y, int nt) {
    __shared__ __align__(16) float Xs[32 * 136];
    __shared__ __align__(16) float Ws[32 * 132];
    const int tid = threadIdx.x;
    const int tn8 = (tid >> 4) * 8;
    const int tm4 = (tid & 15) * 4;
    int b = blockIdx.x;
    int xcd = b & 7, slot = b >> 3;
    int tile = (slot / 3) * 8 + xcd;  // ct=0/1/2 of a tile share the XCD (adjacent slots)
    int ct = slot % 3;
    if (tile >= nt) return;  // block-uniform early exit (before any barrier)
    const int n0 = tile * 128;
    const float* Bm = B + ((ct == 2) ? 0 : 64 + ct * 128);

    float acc[8][8];
#pragma unroll
    for (int a = 0; a < 8; a++)
#pragma unroll
        for (int c = 0; c < 8; c++) acc[a][c] = 0.f;

    for (int kk = 0; kk < 128; kk += 32) {
        if (kk) __syncthreads();
        for (int i = tid; i < 128 * 8; i += 256) {  // Xs: 128 rows x 8 float4 (swizzled transpose)
            int nl = i >> 3, kq = i & 7;
            float4 v = make_float4(0.f, 0.f, 0.f, 0.f);
            if (n0 + nl < NN)
                v = *reinterpret_cast<const float4*>(X + (size_t)(n0 + nl) * 128 + kk + 4 * kq);
            int col = (nl + 4 * kq) & 127;
            Xs[(4 * kq + 0) * 136 + col] = v.x;
            Xs[(4 * kq + 1) * 136 + col] = v.y;
            Xs[(4 * kq + 2) * 136 + col] = v.z;
            Xs[(4 * kq + 3) * 136 + col] = v.w;
        }
        for (int i = tid; i < 32 * 32; i += 256) {  // Ws: 32 k-rows x 128 cols
            int kl = i >> 5, cq = i & 31;
            float4 v = *reinterpret_cast<const float4*>(Bm + (size_t)(kk + kl) * 320 + 4 * cq);
            *reinterpret_cast<float4*>(&Ws[kl * 132 + 4 * cq]) = v;
        }
        __syncthreads();
#pragma unroll 2
        for (int k = 0; k < 32; k++) {
            float4 xq0 = *reinterpret_cast<const float4*>(&Xs[k * 136 + ((tn8 + (k & ~3)) & 127)]);
            float4 xq1 = *reinterpret_cast<const float4*>(&Xs[k * 136 + ((tn8 + 4 + (k & ~3)) & 127)]);
            float4 wq0 = *reinterpret_cast<const float4*>(&Ws[k * 132 + tm4]);
            float4 wq1 = *reinterpret_cast<const float4*>(&Ws[k * 132 + 64 + tm4]);
            float xa[8] = {xq0.x, xq0.y, xq0.z, xq0.w, xq1.x, xq1.y, xq1.z, xq1.w};
            float wa[8] = {wq0.x, wq0.y, wq0.z, wq0.w, wq1.x, wq1.y, wq1.z, wq1.w};
#pragma unroll
            for (int a = 0; a < 8; a++)
#pragma unroll
                for (int c = 0; c < 8; c++) acc[a][c] += xa[a] * wa[c];
        }
    }
    if (ct == 2) {  // root panel -> p=0 (x3 region), first half only
#pragma unroll
        for (int a = 0; a < 8; a++) {
            int n = n0 + tn8 + a;
            if (n < NN)
                *reinterpret_cast<float4*>(Y + (size_t)n * 64 + tm4) =
                    make_float4(acc[a][0], acc[a][1], acc[a][2], acc[a][3]);
        }
    } else {  // rel col gc = ct*128 + {tm4, 64+tm4} -> panels p0=1+2ct, p1=2+2ct, col tm4
        float* Yp0 = Y + (size_t)(1 + 2 * ct) * NN * 64;
        float* Yp1 = Y + (size_t)(2 + 2 * ct) * NN * 64;
#pragma unroll
        for (int a = 0; a < 8; a++) {
            int n = n0 + tn8 + a;
            if (n < NN) {
                *reinterpret_cast<float4*>(Yp0 + (size_t)n * 64 + tm4) =
                    make_float4(acc[a][0], acc[a][1], acc[a][2], acc[a][3]);
                *reinterpret_cast<float4*>(Yp1 + (size_t)n * 64 + tm4) =
                    make_float4(acc[a][4], acc[a][5], acc[a][6], acc[a][7]);
            }
        }
    }
}

// ===== skinny matvec: alds[n][j] = sum_c x1[n][c] * U1p[c*64+j], j<8 (replaces 64-col GEMM) =====
__global__ __launch_bounds__(256) void k_alds1(const float* __restrict__ X,
                                               const float* __restrict__ U1p,
                                               float* __restrict__ alds) {
    __shared__ float sUT[8 * 68];  // sUT[j][c] = U1p[c*64 + j]
    int tid = threadIdx.x;
    for (int i = tid; i < 512; i += 256) {
        int j = i >> 6, c = i & 63;
        sUT[j * 68 + c] = U1p[c * 64 + j];
    }
    __syncthreads();
    int lane = tid & 63, wid = tid >> 6;
    int n = blockIdx.x * 32 + wid * 8 + (lane >> 3);
    int q = lane & 7;  // owns c-slice q*8..q*8+7
    float x[8];
    if (n < NN) {
        float4 v0 = *(const float4*)(X + (size_t)n * 64 + q * 8);
        float4 v1 = *(const float4*)(X + (size_t)n * 64 + q * 8 + 4);
        x[0] = v0.x; x[1] = v0.y; x[2] = v0.z; x[3] = v0.w;
        x[4] = v1.x; x[5] = v1.y; x[6] = v1.z; x[7] = v1.w;
    } else {
#pragma unroll
        for (int c = 0; c < 8; c++) x[c] = 0.f;
    }
    float al[8];
#pragma unroll
    for (int j = 0; j < 8; j++) {
        const float* u = &sUT[j * 68 + q * 8];
        float s = 0.f;
#pragma unroll
        for (int c = 0; c < 8; c++) s += x[c] * u[c];
        al[j] = s;
    }
#pragma unroll
    for (int m = 1; m < 8; m <<= 1)
#pragma unroll
        for (int j = 0; j < 8; j++) al[j] += __shfl_xor(al[j], m);
    if (n < NN) alds[(size_t)n * 8 + q] = al[q];
}

// ===== skinny final: out[n][c<16] = tanh(relu(0.25*sum_k msg2[n][k]*Wstk[k][c] + bg2[c])) =====
__global__ __launch_bounds__(256) void k_final(const float* __restrict__ Xm,
                                               const float* __restrict__ Wstk,
                                               const float* __restrict__ bg2,
                                               float* __restrict__ out) {
    __shared__ float sWT[16 * 132];  // sWT[c][k] = Wstk[k*64 + c]
    int tid = threadIdx.x;
    for (int i = tid; i < 2048; i += 256) {
        int c = i >> 7, k = i & 127;
        sWT[c * 132 + k] = Wstk[k * 64 + c];
    }
    __syncthreads();
    int lane = tid & 63, wid = tid >> 6;
    int n = blockIdx.x * 32 + wid * 8 + (lane >> 3);
    int q = lane & 7;  // owns k in {t*32 + q*4 + s}: conflict-free q*4 stride in LDS
    float x[16];
    if (n < NN) {
#pragma unroll
        for (int t = 0; t < 4; t++) {
            float4 v = *(const float4*)(Xm + (size_t)n * 128 + t * 32 + q * 4);
            x[t * 4 + 0] = v.x; x[t * 4 + 1] = v.y; x[t * 4 + 2] = v.z; x[t * 4 + 3] = v.w;
        }
    } else {
#pragma unroll
        for (int k = 0; k < 16; k++) x[k] = 0.f;
    }
    float al[16];
#pragma unroll
    for (int c = 0; c < 16; c++) {
        float s = 0.f;
#pragma unroll
        for (int t = 0; t < 4; t++) {
            const float* w = &sWT[c * 132 + t * 32 + q * 4];
            s += x[t * 4 + 0] * w[0] + x[t * 4 + 1] * w[1] + x[t * 4 + 2] * w[2] +
                 x[t * 4 + 3] * w[3];
        }
        al[c] = s;
    }
#pragma unroll
    for (int m = 1; m < 8; m <<= 1)
#pragma unroll
        for (int c = 0; c < 16; c++) al[c] += __shfl_xor(al[c], m);
    if (n < NN && q < 4) {
        float4 bv = *(const float4*)(bg2 + q * 4);
        float4 v;
        v.x = tanhf(fmaxf(0.25f * al[q * 4 + 0] + bv.x, 0.f));
        v.y = tanhf(fmaxf(0.25f * al[q * 4 + 1] + bv.y, 0.f));
        v.z = tanhf(fmaxf(0.25f * al[q * 4 + 2] + bv.z, 0.f));
        v.w = tanhf(fmaxf(0.25f * al[q * 4 + 3] + bv.w, 0.f));
        *(float4*)(out + (size_t)n * 16 + q * 4) = v;
    }
}

// ===== aggregate 2 + fused alds2: 8 edge-groups x 8 lanes; x3 stride 64; alds epilogue =====
__global__ __launch_bounds__(256) void k_agg2(const int* __restrict__ rp,
                                              const int* __restrict__ srcs2,
                                              const float* __restrict__ y,
                                              const float* __restrict__ bias,
                                              const float* __restrict__ U2p,
                                              float* __restrict__ x3,
                                              float* __restrict__ alds) {
    __shared__ float sh_inv[4][8];
    int wid = threadIdx.x >> 6, lane = threadIdx.x & 63;
    int n = blockIdx.x * 4 + wid;
    int rpv = (lane <= 8) ? rp[n * RR + lane] : 0;
    int nxt = __shfl(rpv, (lane + 1) & 63);
    if (lane < 8) sh_inv[wid][lane] = 1.f / (float)((nxt - rpv) > 0 ? (nxt - rpv) : 1);
    int q = lane & 7;
    int beg = rp[n * RR], end = rp[n * RR + RR];
    float4 acc = make_float4(0.f, 0.f, 0.f, 0.f);
    int k = beg + (lane >> 3);
    for (; k + 8 < end; k += 16) {
        int key0 = srcs2[k], key1 = srcs2[k + 8];
        int s0 = key0 >> 3, s1 = key1 >> 3;
        int g0 = key0 & 7, g1 = key1 & 7;
        float e0 = sh_inv[wid][g0], e1 = sh_inv[wid][g1];
        float4 v0 = *(const float4*)(y + ((size_t)(g0 >> 1) * NN + s0) * 64 + (g0 & 1) * 32 + q * 4);
        float4 v1 = *(const float4*)(y + ((size_t)(g1 >> 1) * NN + s1) * 64 + (g1 & 1) * 32 + q * 4);
        fmacc(acc, v0, e0);
        fmacc(acc, v1, e1);
    }
    if (k < end) {
        int key0 = srcs2[k];
        int s0 = key0 >> 3;
        int g0 = key0 & 7;
        float4 v0 = *(const float4*)(y + ((size_t)(g0 >> 1) * NN + s0) * 64 + (g0 & 1) * 32 + q * 4);
        fmacc(acc, v0, sh_inv[wid][g0]);
    }
    red4(acc, 8);
    red4(acc, 16);
    red4(acc, 32);
    if (lane < 8) {
        float4 prev = *(const float4*)(x3 + (size_t)n * 64 + q * 4);
        float4 b = *(const float4*)(bias + q * 4);
        float4 v;
        v.x = fmaxf(prev.x + acc.x + b.x, 0.f);
        v.y = fmaxf(prev.y + acc.y + b.y, 0.f);
        v.z = fmaxf(prev.z + acc.z + b.z, 0.f);
        v.w = fmaxf(prev.w + acc.w + b.w, 0.f);
        *(float4*)(x3 + (size_t)n * 64 + q * 4) = v;
        // fused alds2: al[j] = sum_c x3[n][c] * U2p[c*64+j], c = q*4..q*4+3 per lane
        float al[8];
#pragma unroll
        for (int j = 0; j < 8; j++) {
            al[j] = fmaf(v.x, U2p[(q * 4 + 0) * 64 + j],
                    fmaf(v.y, U2p[(q * 4 + 1) * 64 + j],
                    fmaf(v.z, U2p[(q * 4 + 2) * 64 + j],
                         v.w * U2p[(q * 4 + 3) * 64 + j])));
        }
#pragma unroll
        for (int m = 1; m < 8; m <<= 1) {
#pragma unroll
            for (int j = 0; j < 8; j++) al[j] += __shfl_xor(al[j], m);
        }
        alds[n * 8 + q] = al[q];
    }
}

// ===== fused GAT aggregation in input space; alds[n][8] = (als[0..3], ald[0..3]) =====
template <int F, int LDX = F>
__global__ __launch_bounds__(256) void k_gatx(const int* __restrict__ rp,
                                              const int* __restrict__ srcs2,
                                              const float* __restrict__ alds,
                                              const float* __restrict__ X,
                                              float* __restrict__ msg) {
    constexpr int G = F / 4;    // lanes per edge-group (16 or 8)
    constexpr int NG = 64 / G;  // groups per wave (4 or 8)
    int wid = threadIdx.x >> 6, lane = threadIdx.x & 63;
    int n = blockIdx.x * 4 + wid;
    if (n >= NN) return;
    int g = lane / G, q = lane % G;
    float4 ald4 = *(const float4*)(alds + n * 8 + 4);
    float4 acc0 = make_float4(0.f, 0.f, 0.f, 0.f);
    float4 acc1 = acc0, acc2 = acc0, acc3 = acc0;
    float4 z = make_float4(0.f, 0.f, 0.f, 0.f);
    if (g == 0) {  // self loop
        float4 a4 = *(const float4*)(alds + n * 8);
        float4 xv = *(const float4*)(X + (size_t)n * LDX + q * 4);
        float p0 = __expf(leaky(a4.x + ald4.x));
        float p1 = __expf(leaky(a4.y + ald4.y));
        float p2 = __expf(leaky(a4.z + ald4.z));
        float p3 = __expf(leaky(a4.w + ald4.w));
        z = make_float4(p0, p1, p2, p3);
        fmacc(acc0, xv, p0);
        fmacc(acc1, xv, p1);
        fmacc(acc2, xv, p2);
        fmacc(acc3, xv, p3);
    }
    int beg = rp[n * RR], end = rp[n * RR + RR];
    int k = beg + g;
    for (; k + NG < end; k += 2 * NG) {
        int s0 = srcs2[k] >> 3, s1 = srcs2[k + NG] >> 3;
        float4 a0 = *(const float4*)(alds + s0 * 8);
        float4 a1 = *(const float4*)(alds + s1 * 8);
        float4 x0 = *(const float4*)(X + (size_t)s0 * LDX + q * 4);
        float4 x1v = *(const float4*)(X + (size_t)s1 * LDX + q * 4);
        float p00 = __expf(leaky(a0.x + ald4.x)), p01 = __expf(leaky(a0.y + ald4.y));
        float p02 = __expf(leaky(a0.z + ald4.z)), p03 = __expf(leaky(a0.w + ald4.w));
        float p10 = __expf(leaky(a1.x + ald4.x)), p11 = __expf(leaky(a1.y + ald4.y));
        float p12 = __expf(leaky(a1.z + ald4.z)), p13 = __expf(leaky(a1.w + ald4.w));
        z.x += p00 + p10;
        z.y += p01 + p11;
        z.z += p02 + p12;
        z.w += p03 + p13;
        fmacc(acc0, x0, p00);
        fmacc(acc1, x0, p01);
        fmacc(acc2, x0, p02);
        fmacc(acc3, x0, p03);
        fmacc(acc0, x1v, p10);
        fmacc(acc1, x1v, p11);
        fmacc(acc2, x1v, p12);
        fmacc(acc3, x1v, p13);
    }
    if (k < end) {
        int s0 = srcs2[k] >> 3;
        float4 a0 = *(const float4*)(alds + s0 * 8);
        float4 x0 = *(const float4*)(X + (size_t)s0 * LDX + q * 4);
        float p00 = __expf(leaky(a0.x + ald4.x)), p01 = __expf(leaky(a0.y + ald4.y));
        float p02 = __expf(leaky(a0.z + ald4.z)), p03 = __expf(leaky(a0.w + ald4.w));
        z.x += p00;
        z.y += p01;
        z.z += p02;
        z.w += p03;
        fmacc(acc0, x0, p00);
        fmacc(acc1, x0, p01);
        fmacc(acc2, x0, p02);
        fmacc(acc3, x0, p03);
    }
#pragma unroll
    for (int m = G; m < 64; m <<= 1) {
        red4(acc0, m);
        red4(acc1, m);
        red4(acc2, m);
        red4(acc3, m);
        red4(z, m);
    }
    if (g == 0) {
        float4 iz = make_float4(1.f / z.x, 1.f / z.y, 1.f / z.z, 1.f / z.w);
        float* mp = msg + (size_t)n * 4 * F + q * 4;
        *(float4*)(mp + 0 * F) = make_float4(acc0.x * iz.x, acc0.y * iz.x, acc0.z * iz.x, acc0.w * iz.x);
        *(float4*)(mp + 1 * F) = make_float4(acc1.x * iz.y, acc1.y * iz.y, acc1.z * iz.y, acc1.w * iz.y);
        *(float4*)(mp + 2 * F) = make_float4(acc2.x * iz.z, acc2.y * iz.z, acc2.z * iz.z, acc2.w * iz.z);
        *(float4*)(mp + 3 * F) = make_float4(acc3.x * iz.w, acc3.y * iz.w, acc3.z * iz.w, acc3.w * iz.w);
    }
}

extern "C" void kernel_launch(void* const* d_in, const int* in_sizes, int n_in,
                              void* d_out, int out_size, void* d_ws, size_t ws_size,
                              hipStream_t stream) {
    const float* x      = (const float*)d_in[0];
    const int*   ei     = (const int*)d_in[1];
    const int*   et     = (const int*)d_in[2];
    const float* basis1 = (const float*)d_in[3];
    const float* comp1  = (const float*)d_in[4];
    const float* root1  = (const float*)d_in[5];
    const float* brg1   = (const float*)d_in[6];
    const float* wg1    = (const float*)d_in[7];
    const float* asrc1  = (const float*)d_in[8];
    const float* adst1  = (const float*)d_in[9];
    const float* bg1    = (const float*)d_in[10];
    const float* basis2 = (const float*)d_in[11];
    const float* comp2  = (const float*)d_in[12];
    const float* root2  = (const float*)d_in[13];
    const float* brg2   = (const float*)d_in[14];
    const float* wg2    = (const float*)d_in[15];
    const float* asrc2  = (const float*)d_in[16];
    const float* adst2  = (const float*)d_in[17];
    const float* bg2    = (const float*)d_in[18];
    const int* src = ei;
    const int* dst = ei + EE;
    float* out = (float*)d_out;

    // ---- int region ----
    int* wsi = (int*)d_ws;
    size_t ioff = 0;
    auto ialloc = [&](size_t n) { int* p = wsi + ioff; ioff += (n + 3) & ~(size_t)3; return p; };
    int* cnt2 = ialloc(SEGS);  // reused as fill cursors (wo)
    int* rp   = ialloc(SEGS + 1);
    int* bsum = ialloc(2048);
    int* srcs2 = ialloc(EE);
    int* wo = cnt2;
    // ---- float region ----
    float* wsf = (float*)(wsi + ioff);
    size_t total_f = (ws_size - ioff * sizeof(int)) / sizeof(float);
    size_t P_f = (size_t)NN * 320;
    size_t need_f = P_f + (size_t)NN * 128
                  + 40960 + 20480 + 16384 + 8192 + 4096 + 2048
                  + (size_t)NN * 8 + 64;
    if (total_f < need_f) return;  // loud fail: output stays zero
    size_t foff = 0;
    auto falloc = [&](size_t n) { float* p = wsf + foff; foff += (n + 3) & ~(size_t)3; return p; };
    float* P      = falloc(P_f);
    float* x2     = falloc((size_t)NN * 128);
    float* Wcat2e = falloc(40960);           // [128][320]: root2(pad) | W_r pairs
    float* Wb1    = falloc(20480);           // [320][64]: basis1 rows | root1 rows
    float* wg1r   = falloc(16384);
    float* Wstk   = falloc(8192);
    float* U1p    = falloc(4096);
    float* U2p    = falloc(2048);
    float* alds   = falloc((size_t)NN * 8);
    float* Ubuf = P;                  // L1 basis-gather output [n][320]
    float* x1   = x2 + (size_t)NN * 64;  // dead before msg1-gemm overwrites x2 region
    float* msg1 = P;                  // [n][4][64] (U dead after u-gemm)
    float* x3   = P;                  // stride 64, cols 32-63 pad (L3)
    float* ybuf3 = P + (size_t)NN * 64;  // L3 transform out, 4*NN*64
    float* msg2 = P + (size_t)NN * 64;   // [n][4][32] (ybuf3 dead after agg2; disjoint from x3)

    const int EB = (EE + 255) / 256;
    const int NB4 = (NN + 3) / 4;    // NN % 4 == 0 -> exact
    const int NB32 = (NN + 31) / 32; // 1563 (skinny matvec blocks, 32 nodes each)
    const int NT2 = (NN + 127) / 128;       // 391 (big gemm tiles)
    const int NT28 = ((NT2 + 7) / 8) * 8;   // 392: XCD-swizzle rounding

    // ---- CSR build ----
    hipMemsetAsync(cnt2, 0, SEGS * sizeof(int), stream);
    k_count2<<<EB, 256, 0, stream>>>(dst, et, cnt2);
    k_scanA<<<NBLK, 256, 0, stream>>>(cnt2, rp, bsum);
    k_scanB<<<1, 256, 0, stream>>>(bsum);
    k_scanC<<<NBLK, 256, 0, stream>>>(rp, bsum, wo);
    k_fill<<<EB, 256, 0, stream>>>(src, dst, et, wo, srcs2);
    k_prep<<<(92160 + 255) / 256, 256, 0, stream>>>(
        wg1, wg2, root1, root2, basis1, basis2, comp2, asrc1, adst1, asrc2, adst2,
        Wcat2e, wg1r, Wstk, U1p, U2p, Wb1);

    // ---- layer 1: RGCN(64->64)+relu via basis-space gather + one K=320 GEMM ----
    k_gagg1<<<NB4, 256, 0, stream>>>(rp, srcs2, comp1, x, Ubuf);
    k_gemm128<320, 64, 2><<<dim3(NT2, 1), 256, 0, stream>>>(Ubuf, 320, 0, Wb1, 64, 0,
                                                            x1, 64, 0, brg1, 0, NT2, 0);

    // ---- layer 2: GAT(64 -> 4x32 concat), aggregated in input space ----
    k_alds1<<<NB32, 256, 0, stream>>>(x1, U1p, alds);
    k_gatx<64><<<NB4, 256, 0, stream>>>(rp, srcs2, alds, x1, msg1);
    k_gemm128<64, 32><<<dim3(NT2, 4), 256, 0, stream>>>(msg1, 256, 64, wg1r, 64, 4096,
                                                        x2, 128, 32, bg1, 32, NT2, 0);

    // ---- layer 3: RGCN(128->32)+relu; one fused kernel: root (ct=2) + rel panels (ct=0/1) ----
    k_gemmL3<<<NT28 * 3, 256, 0, stream>>>(x2, Wcat2e, P, NT2);
    k_agg2<<<NB4, 256, 0, stream>>>(rp, srcs2, ybuf3, brg2, U2p, x3, alds);

    // ---- layer 4: GAT(32 -> 4x16, mean heads) + relu + tanh (alds fused into agg2) ----
    k_gatx<32, 64><<<NB4, 256, 0, stream>>>(rp, srcs2, alds, x3, msg2);
    k_final<<<NB32, 256, 0, stream>>>(msg2, Wstk, bg2, out);
}

// Round 3
// 540.107 us; speedup vs baseline: 1.0044x; 1.0044x over previous
//
#include <hip/hip_runtime.h>
#include <math.h>

#define NN 50000
#define EE 800000
#define RR 8
#define SLOPE 0.2f
#define SEGS (NN * RR)            /* 400000 per-(node,relation) segments */
#define NBLK ((SEGS + 255) / 256) /* 1563 scan blocks */

__device__ __forceinline__ float leaky(float v) { return v >= 0.f ? v : SLOPE * v; }

__device__ __forceinline__ void fmacc(float4& a, const float4& v, float p) {
    a.x = fmaf(v.x, p, a.x);
    a.y = fmaf(v.y, p, a.y);
    a.z = fmaf(v.z, p, a.z);
    a.w = fmaf(v.w, p, a.w);
}

__device__ __forceinline__ void red4(float4& a, int m) {
    a.x += __shfl_xor(a.x, m);
    a.y += __shfl_xor(a.y, m);
    a.z += __shfl_xor(a.z, m);
    a.w += __shfl_xor(a.w, m);
}

// ============================ CSR build ============================
__global__ void k_count2(const int* __restrict__ dst, const int* __restrict__ et,
                         int* __restrict__ cnt2) {
    int e = blockIdx.x * 256 + threadIdx.x;
    if (e < EE) atomicAdd(&cnt2[dst[e] * RR + et[e]], 1);
}

__global__ void k_scanA(const int* __restrict__ cnt2, int* __restrict__ rp,
                        int* __restrict__ bsum) {
    __shared__ int sh[256];
    int t = threadIdx.x;
    int i = blockIdx.x * 256 + t;
    int v = (i < SEGS) ? cnt2[i] : 0;
    sh[t] = v;
    __syncthreads();
    for (int off = 1; off < 256; off <<= 1) {
        int u = (t >= off) ? sh[t - off] : 0;
        __syncthreads();
        sh[t] += u;
        __syncthreads();
    }
    if (i < SEGS) rp[i] = sh[t] - v;
    if (t == 255) bsum[blockIdx.x] = sh[255];
}

__global__ void k_scanB(int* __restrict__ bsum) {
    __shared__ int sh[256];
    int t = threadIdx.x;
    int loc[8];
    int s = 0;
#pragma unroll
    for (int i = 0; i < 8; i++) {
        int idx = t * 8 + i;
        int v = (idx < NBLK) ? bsum[idx] : 0;
        loc[i] = v;
        s += v;
    }
    sh[t] = s;
    __syncthreads();
    for (int off = 1; off < 256; off <<= 1) {
        int u = (t >= off) ? sh[t - off] : 0;
        __syncthreads();
        sh[t] += u;
        __syncthreads();
    }
    int run = sh[t] - s;
#pragma unroll
    for (int i = 0; i < 8; i++) {
        int idx = t * 8 + i;
        if (idx < NBLK) {
            int v = loc[i];
            bsum[idx] = run;
            run += v;
        }
    }
}

__global__ void k_scanC(int* __restrict__ rp, const int* __restrict__ bsum,
                        int* __restrict__ wo) {
    int i = blockIdx.x * 256 + threadIdx.x;
    if (i < SEGS) {
        int v = rp[i] + bsum[blockIdx.x];
        rp[i] = v;
        wo[i] = v;
    }
    if (i == 0) rp[SEGS] = EE;
}

// fill packed keys: srcs2[pos] = src*8 + relation (single scattered store per edge)
__global__ void k_fill(const int* __restrict__ src, const int* __restrict__ dst,
                       const int* __restrict__ et, int* __restrict__ wo,
                       int* __restrict__ srcs2) {
    int e = blockIdx.x * 256 + threadIdx.x;
    if (e >= EE) return;
    int r = et[e];
    int seg = dst[e] * RR + r;
    int pos = atomicAdd(&wo[seg], 1);
    srcs2[pos] = (src[e] << 3) | r;
}

// ==== prep (merged): padded weights, logit projections, stacked Wb1, Wcat2e compose ====
__global__ void k_prep(const float* __restrict__ wg1, const float* __restrict__ wg2,
                       const float* __restrict__ root1, const float* __restrict__ root2,
                       const float* __restrict__ basis1, const float* __restrict__ basis2,
                       const float* __restrict__ comp2,
                       const float* __restrict__ asrc1, const float* __restrict__ adst1,
                       const float* __restrict__ asrc2, const float* __restrict__ adst2,
                       float* __restrict__ Wcat2e, float* __restrict__ wg1r,
                       float* __restrict__ Wstk, float* __restrict__ U1p,
                       float* __restrict__ U2p, float* __restrict__ Wb1) {
    int idx = blockIdx.x * 256 + threadIdx.x;
    if (idx < 16384) {  // wg1r[h][k][c] (c<32 valid)
        int h = idx >> 12, kc = idx & 4095;
        int k = kc >> 6, c = kc & 63;
        wg1r[idx] = (c < 32) ? wg1[k * 128 + h * 32 + c] : 0.f;
    } else if (idx < 24576) {  // Wstk[h*32+k][c] = wg2[k][h*16+c] (c<16 valid)
        int j = idx - 16384;
        int row = j >> 6, c = j & 63;
        int h = row >> 5, k = row & 31;
        Wstk[j] = (c < 16) ? wg2[k * 64 + h * 16 + c] : 0.f;
    } else if (idx < 32768) {  // Wcat2e root block: [128][col 0-63] = root2 zero-padded
        int j = idx - 24576;
        int k = j >> 6, c = j & 63;
        Wcat2e[k * 320 + c] = (c < 32) ? root2[k * 32 + c] : 0.f;
    } else if (idx < 36864) {  // U1p[k][j]: j<4 src head j, 4<=j<8 dst head j-4, else 0
        int j0 = idx - 32768;
        int k = j0 >> 6, j = j0 & 63;
        float s = 0.f;
        if (j < 8) {
            int h = j & 3;
            const float* a = (j < 4) ? asrc1 : adst1;
            for (int c = 0; c < 32; c++) s += wg1[k * 128 + h * 32 + c] * a[h * 32 + c];
        }
        U1p[j0] = s;
    } else if (idx < 38912) {  // U2p[k][j]
        int j0 = idx - 36864;
        int k = j0 >> 6, j = j0 & 63;
        float s = 0.f;
        if (j < 8) {
            int h = j & 3;
            const float* a = (j < 4) ? asrc2 : adst2;
            for (int c = 0; c < 16; c++) s += wg2[k * 64 + h * 16 + c] * a[h * 16 + c];
        }
        U2p[j0] = s;
    } else if (idx < 55296) {  // Wb1 rows 0-255 = basis1 [4][64][64] flat copy
        Wb1[idx - 38912] = basis1[idx - 38912];
    } else if (idx < 59392) {  // Wb1 rows 256-319 = root1
        Wb1[idx - 38912] = root1[idx - 55296];
    } else if (idx < 92160) {  // Wcat2e basis-composed block: [128][col 64-319]
        int j = idx - 59392;
        int i = j >> 8, rc = j & 255;
        int r = rc >> 5, o = rc & 31;
        float acc = 0.f;
#pragma unroll
        for (int b = 0; b < 4; b++) acc += comp2[r * 4 + b] * basis2[b * 4096 + i * 32 + o];
        Wcat2e[i * 320 + 64 + rc] = acc;
    }
}

// ===== L1 basis-space gather: U[n][b][64] = sum_edges comp[r,b]*inv_cnt*x[src]; U[n][4][64]=x[n] =====
__global__ __launch_bounds__(256) void k_gagg1(const int* __restrict__ rp,
                                               const int* __restrict__ srcs2,
                                               const float* __restrict__ comp,
                                               const float* __restrict__ X,
                                               float* __restrict__ U) {
    __shared__ float4 sh_w[4][8];
    int wid = threadIdx.x >> 6, lane = threadIdx.x & 63;
    int n = blockIdx.x * 4 + wid;
    int rpv = (lane <= 8) ? rp[n * RR + lane] : 0;
    int nxt = __shfl(rpv, (lane + 1) & 63);
    if (lane < 8) {
        float inv = 1.f / (float)((nxt - rpv) > 0 ? (nxt - rpv) : 1);
        float4 c = *(const float4*)(comp + lane * 4);
        sh_w[wid][lane] = make_float4(c.x * inv, c.y * inv, c.z * inv, c.w * inv);
    }
    int q = lane & 15;
    int beg = rp[n * RR], end = rp[n * RR + RR];
    float4 a0 = make_float4(0.f, 0.f, 0.f, 0.f);
    float4 a1 = a0, a2 = a0, a3 = a0;
    int k = beg + (lane >> 4);
    for (; k + 4 < end; k += 8) {
        int key0 = srcs2[k], key1 = srcs2[k + 4];
        float4 w0 = sh_w[wid][key0 & 7], w1 = sh_w[wid][key1 & 7];
        float4 v0 = *(const float4*)(X + (size_t)(key0 >> 3) * 64 + q * 4);
        float4 v1 = *(const float4*)(X + (size_t)(key1 >> 3) * 64 + q * 4);
        fmacc(a0, v0, w0.x);
        fmacc(a1, v0, w0.y);
        fmacc(a2, v0, w0.z);
        fmacc(a3, v0, w0.w);
        fmacc(a0, v1, w1.x);
        fmacc(a1, v1, w1.y);
        fmacc(a2, v1, w1.z);
        fmacc(a3, v1, w1.w);
    }
    if (k < end) {
        int key0 = srcs2[k];
        float4 w0 = sh_w[wid][key0 & 7];
        float4 v0 = *(const float4*)(X + (size_t)(key0 >> 3) * 64 + q * 4);
        fmacc(a0, v0, w0.x);
        fmacc(a1, v0, w0.y);
        fmacc(a2, v0, w0.z);
        fmacc(a3, v0, w0.w);
    }
    red4(a0, 16); red4(a0, 32);
    red4(a1, 16); red4(a1, 32);
    red4(a2, 16); red4(a2, 32);
    red4(a3, 16); red4(a3, 32);
    if (lane < 16) {
        float* un = U + (size_t)n * 320;
        *(float4*)(un + 0 * 64 + q * 4) = a0;
        *(float4*)(un + 1 * 64 + q * 4) = a1;
        *(float4*)(un + 2 * 64 + q * 4) = a2;
        *(float4*)(un + 3 * 64 + q * 4) = a3;
        *(float4*)(un + 256 + q * 4) = *(const float4*)(X + (size_t)n * 64 + q * 4);
    }
}

// ============ big tiled GEMM: 128 nodes x 64 cols; Kc=32 (26 KB LDS -> 6 blocks/CU) ============
// Xs transposed+swizzled; mbcnt>0 -> XCD-grouped 1-D grid. ACT: 0=none, 2=relu(x+bias).
// 8x4 acc/thread keeps VGPR<64 (32-wave cap) -- proven local optimum, do not widen (R1/R2).
template <int KTOT, int MV = 64, int ACT = 0>
__global__ __launch_bounds__(256) void k_gemm128(const float* __restrict__ X, int ldX, int xmb,
                                                 const float* __restrict__ B, int ldB, int bmb,
                                                 float* __restrict__ Y, int ldY, size_t ymb,
                                                 const float* __restrict__ bias, int biasmb,
                                                 int nt, int mbcnt) {
    constexpr int Kc = (KTOT < 32) ? KTOT : 32;
    constexpr int KQ = Kc / 4;
    __shared__ __align__(16) float Xs[Kc * 136];
    __shared__ __align__(16) float Ws[Kc * 68];
    const int tid = threadIdx.x;
    const int tn8 = (tid >> 4) * 8;
    const int tm4 = (tid & 15) * 4;
    int tile, mb;
    if (mbcnt) {
        int b = blockIdx.x;
        int xcd = b & 7, slot = b >> 3;
        tile = (slot / mbcnt) * 8 + xcd;
        mb = slot % mbcnt;
        if (tile >= nt) return;  // block-uniform early exit (before any barrier)
    } else {
        tile = blockIdx.x;
        mb = blockIdx.y;
    }
    const int n0 = tile * 128;
    const float* Bm = B + (size_t)mb * bmb;
    const float* Xm = X + (size_t)mb * xmb;

    float acc[8][4];
#pragma unroll
    for (int a = 0; a < 8; a++)
#pragma unroll
        for (int b = 0; b < 4; b++) acc[a][b] = 0.f;

    for (int kk = 0; kk < KTOT; kk += Kc) {
        if (kk) __syncthreads();
        for (int i = tid; i < 128 * KQ; i += 256) {
            int nl = i / KQ, kq = i % KQ;
            float4 v = make_float4(0.f, 0.f, 0.f, 0.f);
            if (n0 + nl < NN)
                v = *reinterpret_cast<const float4*>(Xm + (size_t)(n0 + nl) * ldX + kk + 4 * kq);
            int col = (nl + 4 * kq) & 127;
            Xs[(4 * kq + 0) * 136 + col] = v.x;
            Xs[(4 * kq + 1) * 136 + col] = v.y;
            Xs[(4 * kq + 2) * 136 + col] = v.z;
            Xs[(4 * kq + 3) * 136 + col] = v.w;
        }
        for (int i = tid; i < Kc * 16; i += 256) {
            int kl = i >> 4, cq = i & 15;
            float4 v = *reinterpret_cast<const float4*>(Bm + (size_t)(kk + kl) * ldB + 4 * cq);
            *reinterpret_cast<float4*>(&Ws[kl * 68 + 4 * cq]) = v;
        }
        __syncthreads();
#pragma unroll 4
        for (int k = 0; k < Kc; k++) {
            float4 xq0 = *reinterpret_cast<const float4*>(&Xs[k * 136 + ((tn8 + (k & ~3)) & 127)]);
            float4 xq1 = *reinterpret_cast<const float4*>(&Xs[k * 136 + ((tn8 + 4 + (k & ~3)) & 127)]);
            float4 wq = *reinterpret_cast<const float4*>(&Ws[k * 68 + tm4]);
            float xa[8] = {xq0.x, xq0.y, xq0.z, xq0.w, xq1.x, xq1.y, xq1.z, xq1.w};
            float wa[4] = {wq.x, wq.y, wq.z, wq.w};
#pragma unroll
            for (int a = 0; a < 8; a++)
#pragma unroll
                for (int b = 0; b < 4; b++) acc[a][b] += xa[a] * wa[b];
        }
    }
    if (MV == 64 || tm4 < MV) {
        float4 bv = make_float4(0.f, 0.f, 0.f, 0.f);
        if (bias) bv = *reinterpret_cast<const float4*>(bias + (size_t)mb * biasmb + tm4);
#pragma unroll
        for (int a = 0; a < 8; a++) {
            int n = n0 + tn8 + a;
            if (n < NN) {
                float4 v = make_float4(acc[a][0] + bv.x, acc[a][1] + bv.y,
                                       acc[a][2] + bv.z, acc[a][3] + bv.w);
                if (ACT == 2) {
                    v.x = fmaxf(v.x, 0.f);
                    v.y = fmaxf(v.y, 0.f);
                    v.z = fmaxf(v.z, 0.f);
                    v.w = fmaxf(v.w, 0.f);
                }
                *reinterpret_cast<float4*>(Y + (size_t)mb * ymb + (size_t)n * ldY + tm4) = v;
            }
        }
    }
}

// ===== skinny matvec: alds[n][j] = sum_c x1[n][c] * U1p[c*64+j], j<8 (replaces 64-col GEMM) =====
__global__ __launch_bounds__(256) void k_alds1(const float* __restrict__ X,
                                               const float* __restrict__ U1p,
                                               float* __restrict__ alds) {
    __shared__ float sUT[8 * 68];  // sUT[j][c] = U1p[c*64 + j]
    int tid = threadIdx.x;
    for (int i = tid; i < 512; i += 256) {
        int j = i >> 6, c = i & 63;
        sUT[j * 68 + c] = U1p[c * 64 + j];
    }
    __syncthreads();
    int lane = tid & 63, wid = tid >> 6;
    int n = blockIdx.x * 32 + wid * 8 + (lane >> 3);
    int q = lane & 7;  // owns c-slice q*8..q*8+7
    float x[8];
    if (n < NN) {
        float4 v0 = *(const float4*)(X + (size_t)n * 64 + q * 8);
        float4 v1 = *(const float4*)(X + (size_t)n * 64 + q * 8 + 4);
        x[0] = v0.x; x[1] = v0.y; x[2] = v0.z; x[3] = v0.w;
        x[4] = v1.x; x[5] = v1.y; x[6] = v1.z; x[7] = v1.w;
    } else {
#pragma unroll
        for (int c = 0; c < 8; c++) x[c] = 0.f;
    }
    float al[8];
#pragma unroll
    for (int j = 0; j < 8; j++) {
        const float* u = &sUT[j * 68 + q * 8];
        float s = 0.f;
#pragma unroll
        for (int c = 0; c < 8; c++) s += x[c] * u[c];
        al[j] = s;
    }
#pragma unroll
    for (int m = 1; m < 8; m <<= 1)
#pragma unroll
        for (int j = 0; j < 8; j++) al[j] += __shfl_xor(al[j], m);
    if (n < NN) alds[(size_t)n * 8 + q] = al[q];
}

// ===== skinny final: out[n][c<16] = tanh(relu(0.25*sum_k msg2[n][k]*Wstk[k][c] + bg2[c])) =====
__global__ __launch_bounds__(256) void k_final(const float* __restrict__ Xm,
                                               const float* __restrict__ Wstk,
                                               const float* __restrict__ bg2,
                                               float* __restrict__ out) {
    __shared__ float sWT[16 * 132];  // sWT[c][k] = Wstk[k*64 + c]
    int tid = threadIdx.x;
    for (int i = tid; i < 2048; i += 256) {
        int c = i >> 7, k = i & 127;
        sWT[c * 132 + k] = Wstk[k * 64 + c];
    }
    __syncthreads();
    int lane = tid & 63, wid = tid >> 6;
    int n = blockIdx.x * 32 + wid * 8 + (lane >> 3);
    int q = lane & 7;  // owns k in {t*32 + q*4 + s}: conflict-free q*4 stride in LDS
    float x[16];
    if (n < NN) {
#pragma unroll
        for (int t = 0; t < 4; t++) {
            float4 v = *(const float4*)(Xm + (size_t)n * 128 + t * 32 + q * 4);
            x[t * 4 + 0] = v.x; x[t * 4 + 1] = v.y; x[t * 4 + 2] = v.z; x[t * 4 + 3] = v.w;
        }
    } else {
#pragma unroll
        for (int k = 0; k < 16; k++) x[k] = 0.f;
    }
    float al[16];
#pragma unroll
    for (int c = 0; c < 16; c++) {
        float s = 0.f;
#pragma unroll
        for (int t = 0; t < 4; t++) {
            const float* w = &sWT[c * 132 + t * 32 + q * 4];
            s += x[t * 4 + 0] * w[0] + x[t * 4 + 1] * w[1] + x[t * 4 + 2] * w[2] +
                 x[t * 4 + 3] * w[3];
        }
        al[c] = s;
    }
#pragma unroll
    for (int m = 1; m < 8; m <<= 1)
#pragma unroll
        for (int c = 0; c < 16; c++) al[c] += __shfl_xor(al[c], m);
    if (n < NN && q < 4) {
        float4 bv = *(const float4*)(bg2 + q * 4);
        float4 v;
        v.x = tanhf(fmaxf(0.25f * al[q * 4 + 0] + bv.x, 0.f));
        v.y = tanhf(fmaxf(0.25f * al[q * 4 + 1] + bv.y, 0.f));
        v.z = tanhf(fmaxf(0.25f * al[q * 4 + 2] + bv.z, 0.f));
        v.w = tanhf(fmaxf(0.25f * al[q * 4 + 3] + bv.w, 0.f));
        *(float4*)(out + (size_t)n * 16 + q * 4) = v;
    }
}

// ===== aggregate 2 + fused alds2: 8 edge-groups x 8 lanes; x3 stride 64; alds epilogue =====
__global__ __launch_bounds__(256) void k_agg2(const int* __restrict__ rp,
                                              const int* __restrict__ srcs2,
                                              const float* __restrict__ y,
                                              const float* __restrict__ bias,
                                              const float* __restrict__ U2p,
                                              float* __restrict__ x3,
                                              float* __restrict__ alds) {
    __shared__ float sh_inv[4][8];
    int wid = threadIdx.x >> 6, lane = threadIdx.x & 63;
    int n = blockIdx.x * 4 + wid;
    int rpv = (lane <= 8) ? rp[n * RR + lane] : 0;
    int nxt = __shfl(rpv, (lane + 1) & 63);
    if (lane < 8) sh_inv[wid][lane] = 1.f / (float)((nxt - rpv) > 0 ? (nxt - rpv) : 1);
    int q = lane & 7;
    int beg = rp[n * RR], end = rp[n * RR + RR];
    float4 acc = make_float4(0.f, 0.f, 0.f, 0.f);
    int k = beg + (lane >> 3);
    for (; k + 8 < end; k += 16) {
        int key0 = srcs2[k], key1 = srcs2[k + 8];
        int s0 = key0 >> 3, s1 = key1 >> 3;
        int g0 = key0 & 7, g1 = key1 & 7;
        float e0 = sh_inv[wid][g0], e1 = sh_inv[wid][g1];
        float4 v0 = *(const float4*)(y + ((size_t)(g0 >> 1) * NN + s0) * 64 + (g0 & 1) * 32 + q * 4);
        float4 v1 = *(const float4*)(y + ((size_t)(g1 >> 1) * NN + s1) * 64 + (g1 & 1) * 32 + q * 4);
        fmacc(acc, v0, e0);
        fmacc(acc, v1, e1);
    }
    if (k < end) {
        int key0 = srcs2[k];
        int s0 = key0 >> 3;
        int g0 = key0 & 7;
        float4 v0 = *(const float4*)(y + ((size_t)(g0 >> 1) * NN + s0) * 64 + (g0 & 1) * 32 + q * 4);
        fmacc(acc, v0, sh_inv[wid][g0]);
    }
    red4(acc, 8);
    red4(acc, 16);
    red4(acc, 32);
    if (lane < 8) {
        float4 prev = *(const float4*)(x3 + (size_t)n * 64 + q * 4);
        float4 b = *(const float4*)(bias + q * 4);
        float4 v;
        v.x = fmaxf(prev.x + acc.x + b.x, 0.f);
        v.y = fmaxf(prev.y + acc.y + b.y, 0.f);
        v.z = fmaxf(prev.z + acc.z + b.z, 0.f);
        v.w = fmaxf(prev.w + acc.w + b.w, 0.f);
        *(float4*)(x3 + (size_t)n * 64 + q * 4) = v;
        // fused alds2: al[j] = sum_c x3[n][c] * U2p[c*64+j], c = q*4..q*4+3 per lane
        float al[8];
#pragma unroll
        for (int j = 0; j < 8; j++) {
            al[j] = fmaf(v.x, U2p[(q * 4 + 0) * 64 + j],
                    fmaf(v.y, U2p[(q * 4 + 1) * 64 + j],
                    fmaf(v.z, U2p[(q * 4 + 2) * 64 + j],
                         v.w * U2p[(q * 4 + 3) * 64 + j])));
        }
#pragma unroll
        for (int m = 1; m < 8; m <<= 1) {
#pragma unroll
            for (int j = 0; j < 8; j++) al[j] += __shfl_xor(al[j], m);
        }
        alds[n * 8 + q] = al[q];
    }
}

// ===== fused GAT aggregation in input space; alds[n][8] = (als[0..3], ald[0..3]) =====
template <int F, int LDX = F>
__global__ __launch_bounds__(256) void k_gatx(const int* __restrict__ rp,
                                              const int* __restrict__ srcs2,
                                              const float* __restrict__ alds,
                                              const float* __restrict__ X,
                                              float* __restrict__ msg) {
    constexpr int G = F / 4;    // lanes per edge-group (16 or 8)
    constexpr int NG = 64 / G;  // groups per wave (4 or 8)
    int wid = threadIdx.x >> 6, lane = threadIdx.x & 63;
    int n = blockIdx.x * 4 + wid;
    if (n >= NN) return;
    int g = lane / G, q = lane % G;
    float4 ald4 = *(const float4*)(alds + n * 8 + 4);
    float4 acc0 = make_float4(0.f, 0.f, 0.f, 0.f);
    float4 acc1 = acc0, acc2 = acc0, acc3 = acc0;
    float4 z = make_float4(0.f, 0.f, 0.f, 0.f);
    if (g == 0) {  // self loop
        float4 a4 = *(const float4*)(alds + n * 8);
        float4 xv = *(const float4*)(X + (size_t)n * LDX + q * 4);
        float p0 = __expf(leaky(a4.x + ald4.x));
        float p1 = __expf(leaky(a4.y + ald4.y));
        float p2 = __expf(leaky(a4.z + ald4.z));
        float p3 = __expf(leaky(a4.w + ald4.w));
        z = make_float4(p0, p1, p2, p3);
        fmacc(acc0, xv, p0);
        fmacc(acc1, xv, p1);
        fmacc(acc2, xv, p2);
        fmacc(acc3, xv, p3);
    }
    int beg = rp[n * RR], end = rp[n * RR + RR];
    int k = beg + g;
    for (; k + NG < end; k += 2 * NG) {
        int s0 = srcs2[k] >> 3, s1 = srcs2[k + NG] >> 3;
        float4 a0 = *(const float4*)(alds + s0 * 8);
        float4 a1 = *(const float4*)(alds + s1 * 8);
        float4 x0 = *(const float4*)(X + (size_t)s0 * LDX + q * 4);
        float4 x1v = *(const float4*)(X + (size_t)s1 * LDX + q * 4);
        float p00 = __expf(leaky(a0.x + ald4.x)), p01 = __expf(leaky(a0.y + ald4.y));
        float p02 = __expf(leaky(a0.z + ald4.z)), p03 = __expf(leaky(a0.w + ald4.w));
        float p10 = __expf(leaky(a1.x + ald4.x)), p11 = __expf(leaky(a1.y + ald4.y));
        float p12 = __expf(leaky(a1.z + ald4.z)), p13 = __expf(leaky(a1.w + ald4.w));
        z.x += p00 + p10;
        z.y += p01 + p11;
        z.z += p02 + p12;
        z.w += p03 + p13;
        fmacc(acc0, x0, p00);
        fmacc(acc1, x0, p01);
        fmacc(acc2, x0, p02);
        fmacc(acc3, x0, p03);
        fmacc(acc0, x1v, p10);
        fmacc(acc1, x1v, p11);
        fmacc(acc2, x1v, p12);
        fmacc(acc3, x1v, p13);
    }
    if (k < end) {
        int s0 = srcs2[k] >> 3;
        float4 a0 = *(const float4*)(alds + s0 * 8);
        float4 x0 = *(const float4*)(X + (size_t)s0 * LDX + q * 4);
        float p00 = __expf(leaky(a0.x + ald4.x)), p01 = __expf(leaky(a0.y + ald4.y));
        float p02 = __expf(leaky(a0.z + ald4.z)), p03 = __expf(leaky(a0.w + ald4.w));
        z.x += p00;
        z.y += p01;
        z.z += p02;
        z.w += p03;
        fmacc(acc0, x0, p00);
        fmacc(acc1, x0, p01);
        fmacc(acc2, x0, p02);
        fmacc(acc3, x0, p03);
    }
#pragma unroll
    for (int m = G; m < 64; m <<= 1) {
        red4(acc0, m);
        red4(acc1, m);
        red4(acc2, m);
        red4(acc3, m);
        red4(z, m);
    }
    if (g == 0) {
        float4 iz = make_float4(1.f / z.x, 1.f / z.y, 1.f / z.z, 1.f / z.w);
        float* mp = msg + (size_t)n * 4 * F + q * 4;
        *(float4*)(mp + 0 * F) = make_float4(acc0.x * iz.x, acc0.y * iz.x, acc0.z * iz.x, acc0.w * iz.x);
        *(float4*)(mp + 1 * F) = make_float4(acc1.x * iz.y, acc1.y * iz.y, acc1.z * iz.y, acc1.w * iz.y);
        *(float4*)(mp + 2 * F) = make_float4(acc2.x * iz.z, acc2.y * iz.z, acc2.z * iz.z, acc2.w * iz.z);
        *(float4*)(mp + 3 * F) = make_float4(acc3.x * iz.w, acc3.y * iz.w, acc3.z * iz.w, acc3.w * iz.w);
    }
}

extern "C" void kernel_launch(void* const* d_in, const int* in_sizes, int n_in,
                              void* d_out, int out_size, void* d_ws, size_t ws_size,
                              hipStream_t stream) {
    const float* x      = (const float*)d_in[0];
    const int*   ei     = (const int*)d_in[1];
    const int*   et     = (const int*)d_in[2];
    const float* basis1 = (const float*)d_in[3];
    const float* comp1  = (const float*)d_in[4];
    const float* root1  = (const float*)d_in[5];
    const float* brg1   = (const float*)d_in[6];
    const float* wg1    = (const float*)d_in[7];
    const float* asrc1  = (const float*)d_in[8];
    const float* adst1  = (const float*)d_in[9];
    const float* bg1    = (const float*)d_in[10];
    const float* basis2 = (const float*)d_in[11];
    const float* comp2  = (const float*)d_in[12];
    const float* root2  = (const float*)d_in[13];
    const float* brg2   = (const float*)d_in[14];
    const float* wg2    = (const float*)d_in[15];
    const float* asrc2  = (const float*)d_in[16];
    const float* adst2  = (const float*)d_in[17];
    const float* bg2    = (const float*)d_in[18];
    const int* src = ei;
    const int* dst = ei + EE;
    float* out = (float*)d_out;

    // ---- int region ----
    int* wsi = (int*)d_ws;
    size_t ioff = 0;
    auto ialloc = [&](size_t n) { int* p = wsi + ioff; ioff += (n + 3) & ~(size_t)3; return p; };
    int* cnt2 = ialloc(SEGS);  // reused as fill cursors (wo)
    int* rp   = ialloc(SEGS + 1);
    int* bsum = ialloc(2048);
    int* srcs2 = ialloc(EE);
    int* wo = cnt2;
    // ---- float region ----
    float* wsf = (float*)(wsi + ioff);
    size_t total_f = (ws_size - ioff * sizeof(int)) / sizeof(float);
    size_t P_f = (size_t)NN * 320;
    size_t need_f = P_f + (size_t)NN * 128
                  + 40960 + 20480 + 16384 + 8192 + 4096 + 2048
                  + (size_t)NN * 8 + 64;
    if (total_f < need_f) return;  // loud fail: output stays zero
    size_t foff = 0;
    auto falloc = [&](size_t n) { float* p = wsf + foff; foff += (n + 3) & ~(size_t)3; return p; };
    float* P      = falloc(P_f);
    float* x2     = falloc((size_t)NN * 128);
    float* Wcat2e = falloc(40960);           // [128][320]: root2(pad) | W_r pairs
    float* Wb1    = falloc(20480);           // [320][64]: basis1 rows | root1 rows
    float* wg1r   = falloc(16384);
    float* Wstk   = falloc(8192);
    float* U1p    = falloc(4096);
    float* U2p    = falloc(2048);
    float* alds   = falloc((size_t)NN * 8);
    float* Ubuf = P;                  // L1 basis-gather output [n][320]
    float* x1   = x2 + (size_t)NN * 64;  // dead before msg1-gemm overwrites x2 region
    float* msg1 = P;                  // [n][4][64] (U dead after u-gemm)
    float* x3   = P;                  // stride 64, cols 32-63 pad (never read; MV=32 skips write)
    float* ybuf3 = P + (size_t)NN * 64;  // L3 transform out, 4*NN*64
    float* msg2 = P + (size_t)NN * 64;   // [n][4][32] (ybuf3 dead after agg2; disjoint from x3)

    const int EB = (EE + 255) / 256;
    const int NB4 = (NN + 3) / 4;    // NN % 4 == 0 -> exact
    const int NB32 = (NN + 31) / 32; // 1563 (skinny matvec blocks, 32 nodes each)
    const int NT2 = (NN + 127) / 128;       // 391 (big gemm tiles)
    const int NT28 = ((NT2 + 7) / 8) * 8;   // 392: XCD-swizzle rounding

    // ---- CSR build ----
    hipMemsetAsync(cnt2, 0, SEGS * sizeof(int), stream);
    k_count2<<<EB, 256, 0, stream>>>(dst, et, cnt2);
    k_scanA<<<NBLK, 256, 0, stream>>>(cnt2, rp, bsum);
    k_scanB<<<1, 256, 0, stream>>>(bsum);
    k_scanC<<<NBLK, 256, 0, stream>>>(rp, bsum, wo);
    k_fill<<<EB, 256, 0, stream>>>(src, dst, et, wo, srcs2);
    k_prep<<<(92160 + 255) / 256, 256, 0, stream>>>(
        wg1, wg2, root1, root2, basis1, basis2, comp2, asrc1, adst1, asrc2, adst2,
        Wcat2e, wg1r, Wstk, U1p, U2p, Wb1);

    // ---- layer 1: RGCN(64->64)+relu via basis-space gather + one K=320 GEMM ----
    k_gagg1<<<NB4, 256, 0, stream>>>(rp, srcs2, comp1, x, Ubuf);
    k_gemm128<320, 64, 2><<<dim3(NT2, 1), 256, 0, stream>>>(Ubuf, 320, 0, Wb1, 64, 0,
                                                            x1, 64, 0, brg1, 0, NT2, 0);

    // ---- layer 2: GAT(64 -> 4x32 concat), aggregated in input space ----
    k_alds1<<<NB32, 256, 0, stream>>>(x1, U1p, alds);
    k_gatx<64><<<NB4, 256, 0, stream>>>(rp, srcs2, alds, x1, msg1);
    k_gemm128<64, 32><<<dim3(NT2, 4), 256, 0, stream>>>(msg1, 256, 64, wg1r, 64, 4096,
                                                        x2, 128, 32, bg1, 32, NT2, 0);

    // ---- layer 3: RGCN(128->32)+relu via proven 8x4 k_gemm128, split launches ----
    // relation panels (4 x 64 cols) -> ybuf3, XCD-swizzled
    k_gemm128<128><<<NT28 * 4, 256, 0, stream>>>(x2, 128, 0, Wcat2e + 64, 320, 64,
                                                 ybuf3, 64, (size_t)NN * 64, nullptr, 0, NT2, 4);
    // root panel -> x3 (MV=32: skip dead pad-column writes)
    k_gemm128<128, 32><<<dim3(NT2, 1), 256, 0, stream>>>(x2, 128, 0, Wcat2e, 320, 0,
                                                         P, 64, 0, nullptr, 0, NT2, 0);
    k_agg2<<<NB4, 256, 0, stream>>>(rp, srcs2, ybuf3, brg2, U2p, x3, alds);

    // ---- layer 4: GAT(32 -> 4x16, mean heads) + relu + tanh (alds fused into agg2) ----
    k_gatx<32, 64><<<NB4, 256, 0, stream>>>(rp, srcs2, alds, x3, msg2);
    k_final<<<NB32, 256, 0, stream>>>(msg2, Wstk, bg2, out);
}

// Round 4
// 474.510 us; speedup vs baseline: 1.1433x; 1.1382x over previous
//
#include <hip/hip_runtime.h>
#include <math.h>

#define NN 50000
#define EE 800000
#define RR 8
#define SLOPE 0.2f
#define SEGS (NN * RR)            /* 400000 per-(node,relation) segments */
#define NBLK ((SEGS + 255) / 256) /* 1563 scan blocks */
#define NTW ((NN + 63) / 64)      /* 782 mfma row-tiles (64 rows each) */

typedef __attribute__((ext_vector_type(8))) short bf16x8;
typedef __attribute__((ext_vector_type(4))) float f32x4;

__device__ __forceinline__ float leaky(float v) { return v >= 0.f ? v : SLOPE * v; }

__device__ __forceinline__ void fmacc(float4& a, const float4& v, float p) {
    a.x = fmaf(v.x, p, a.x);
    a.y = fmaf(v.y, p, a.y);
    a.z = fmaf(v.z, p, a.z);
    a.w = fmaf(v.w, p, a.w);
}

__device__ __forceinline__ void red4(float4& a, int m) {
    a.x += __shfl_xor(a.x, m);
    a.y += __shfl_xor(a.y, m);
    a.z += __shfl_xor(a.z, m);
    a.w += __shfl_xor(a.w, m);
}

// split 8 fp32 -> bf16 hi (truncate) + bf16 lo (truncate of exact residual).
// 3-term mfma (AhBh+AlBh+AhBl) then has ~2^-17 relative error (fp32-grade here).
__device__ __forceinline__ void split8(const float4& v0, const float4& v1,
                                       bf16x8& hi, bf16x8& lo) {
    float e[8] = {v0.x, v0.y, v0.z, v0.w, v1.x, v1.y, v1.z, v1.w};
    union { bf16x8 v; unsigned u[4]; } H, L;
#pragma unroll
    for (int j = 0; j < 4; j++) {
        unsigned b0 = __float_as_uint(e[2 * j]), b1 = __float_as_uint(e[2 * j + 1]);
        unsigned h0 = b0 & 0xFFFF0000u, h1 = b1 & 0xFFFF0000u;
        H.u[j] = (h0 >> 16) | h1;
        float l0 = e[2 * j] - __uint_as_float(h0);
        float l1 = e[2 * j + 1] - __uint_as_float(h1);
        L.u[j] = (__float_as_uint(l0) >> 16) | (__float_as_uint(l1) & 0xFFFF0000u);
    }
    hi = H.v;
    lo = L.v;
}

// ============================ CSR build ============================
__global__ void k_count2(const int* __restrict__ dst, const int* __restrict__ et,
                         int* __restrict__ cnt2) {
    int e = blockIdx.x * 256 + threadIdx.x;
    if (e < EE) atomicAdd(&cnt2[dst[e] * RR + et[e]], 1);
}

__global__ void k_scanA(const int* __restrict__ cnt2, int* __restrict__ rp,
                        int* __restrict__ bsum) {
    __shared__ int sh[256];
    int t = threadIdx.x;
    int i = blockIdx.x * 256 + t;
    int v = (i < SEGS) ? cnt2[i] : 0;
    sh[t] = v;
    __syncthreads();
    for (int off = 1; off < 256; off <<= 1) {
        int u = (t >= off) ? sh[t - off] : 0;
        __syncthreads();
        sh[t] += u;
        __syncthreads();
    }
    if (i < SEGS) rp[i] = sh[t] - v;
    if (t == 255) bsum[blockIdx.x] = sh[255];
}

__global__ void k_scanB(int* __restrict__ bsum) {
    __shared__ int sh[256];
    int t = threadIdx.x;
    int loc[8];
    int s = 0;
#pragma unroll
    for (int i = 0; i < 8; i++) {
        int idx = t * 8 + i;
        int v = (idx < NBLK) ? bsum[idx] : 0;
        loc[i] = v;
        s += v;
    }
    sh[t] = s;
    __syncthreads();
    for (int off = 1; off < 256; off <<= 1) {
        int u = (t >= off) ? sh[t - off] : 0;
        __syncthreads();
        sh[t] += u;
        __syncthreads();
    }
    int run = sh[t] - s;
#pragma unroll
    for (int i = 0; i < 8; i++) {
        int idx = t * 8 + i;
        if (idx < NBLK) {
            int v = loc[i];
            bsum[idx] = run;
            run += v;
        }
    }
}

__global__ void k_scanC(int* __restrict__ rp, const int* __restrict__ bsum,
                        int* __restrict__ wo) {
    int i = blockIdx.x * 256 + threadIdx.x;
    if (i < SEGS) {
        int v = rp[i] + bsum[blockIdx.x];
        rp[i] = v;
        wo[i] = v;
    }
    if (i == 0) rp[SEGS] = EE;
}

// fill packed keys: srcs2[pos] = src*8 + relation (single scattered store per edge)
__global__ void k_fill(const int* __restrict__ src, const int* __restrict__ dst,
                       const int* __restrict__ et, int* __restrict__ wo,
                       int* __restrict__ srcs2) {
    int e = blockIdx.x * 256 + threadIdx.x;
    if (e >= EE) return;
    int r = et[e];
    int seg = dst[e] * RR + r;
    int pos = atomicAdd(&wo[seg], 1);
    srcs2[pos] = (src[e] << 3) | r;
}

// ==== prep (merged): padded weights, logit projections, stacked Wb1, Wcat2e compose ====
__global__ void k_prep(const float* __restrict__ wg1, const float* __restrict__ wg2,
                       const float* __restrict__ root1, const float* __restrict__ root2,
                       const float* __restrict__ basis1, const float* __restrict__ basis2,
                       const float* __restrict__ comp2,
                       const float* __restrict__ asrc1, const float* __restrict__ adst1,
                       const float* __restrict__ asrc2, const float* __restrict__ adst2,
                       float* __restrict__ Wcat2e, float* __restrict__ wg1r,
                       float* __restrict__ Wstk, float* __restrict__ U1p,
                       float* __restrict__ U2p, float* __restrict__ Wb1) {
    int idx = blockIdx.x * 256 + threadIdx.x;
    if (idx < 16384) {  // wg1r[h][k][c] (c<32 valid)
        int h = idx >> 12, kc = idx & 4095;
        int k = kc >> 6, c = kc & 63;
        wg1r[idx] = (c < 32) ? wg1[k * 128 + h * 32 + c] : 0.f;
    } else if (idx < 24576) {  // Wstk[h*32+k][c] = wg2[k][h*16+c] (c<16 valid)
        int j = idx - 16384;
        int row = j >> 6, c = j & 63;
        int h = row >> 5, k = row & 31;
        Wstk[j] = (c < 16) ? wg2[k * 64 + h * 16 + c] : 0.f;
    } else if (idx < 32768) {  // Wcat2e root block: [128][col 0-63] = root2 zero-padded
        int j = idx - 24576;
        int k = j >> 6, c = j & 63;
        Wcat2e[k * 320 + c] = (c < 32) ? root2[k * 32 + c] : 0.f;
    } else if (idx < 36864) {  // U1p[k][j]: j<4 src head j, 4<=j<8 dst head j-4, else 0
        int j0 = idx - 32768;
        int k = j0 >> 6, j = j0 & 63;
        float s = 0.f;
        if (j < 8) {
            int h = j & 3;
            const float* a = (j < 4) ? asrc1 : adst1;
            for (int c = 0; c < 32; c++) s += wg1[k * 128 + h * 32 + c] * a[h * 32 + c];
        }
        U1p[j0] = s;
    } else if (idx < 38912) {  // U2p[k][j]
        int j0 = idx - 36864;
        int k = j0 >> 6, j = j0 & 63;
        float s = 0.f;
        if (j < 8) {
            int h = j & 3;
            const float* a = (j < 4) ? asrc2 : adst2;
            for (int c = 0; c < 16; c++) s += wg2[k * 64 + h * 16 + c] * a[h * 16 + c];
        }
        U2p[j0] = s;
    } else if (idx < 55296) {  // Wb1 rows 0-255 = basis1 [4][64][64] flat copy
        Wb1[idx - 38912] = basis1[idx - 38912];
    } else if (idx < 59392) {  // Wb1 rows 256-319 = root1
        Wb1[idx - 38912] = root1[idx - 55296];
    } else if (idx < 92160) {  // Wcat2e basis-composed block: [128][col 64-319]
        int j = idx - 59392;
        int i = j >> 8, rc = j & 255;
        int r = rc >> 5, o = rc & 31;
        float acc = 0.f;
#pragma unroll
        for (int b = 0; b < 4; b++) acc += comp2[r * 4 + b] * basis2[b * 4096 + i * 32 + o];
        Wcat2e[i * 320 + 64 + rc] = acc;
    }
}

// ==== pack weights into bf16 hi/lo MFMA fragment order ====
// frag element r of lane (g=lane>>4, m=lane&15): B[k = kc*32 + g*8 + r][col = ct*16 + m].
// pair layout: [pairIdx = ct*NKC + kc][hi:0/lo:1][lane][8] -> 1024 shorts per pair.
// pairs: Wb1 (NCT=4,NKC=10) -> 40 | wg1r 4 heads x (NCT=2,NKC=2) -> 16 | Wcat2e 5 panels x (NCT=4,NKC=4) -> 80
__global__ void k_pack(const float* __restrict__ Wb1, const float* __restrict__ wg1r,
                       const float* __restrict__ Wcat, short* __restrict__ pWb1,
                       short* __restrict__ pwg1r, short* __restrict__ pWcat) {
    int u = blockIdx.x * 256 + threadIdx.x;
    int lane = u & 63, pair = u >> 6;
    if (pair >= 136) return;
    int m = lane & 15, g = lane >> 4;
    const float* src;
    int ldB, col, k0;
    short* dst;
    if (pair < 40) {
        int ct = pair / 10, kc = pair % 10;
        src = Wb1; ldB = 64; col = ct * 16 + m; k0 = kc * 32 + g * 8;
        dst = pWb1 + pair * 1024 + lane * 8;
    } else if (pair < 56) {
        int q = pair - 40;
        int h = q >> 2, lp = q & 3, ct = lp >> 1, kc = lp & 1;
        src = wg1r + h * 4096; ldB = 64; col = ct * 16 + m; k0 = kc * 32 + g * 8;
        dst = pwg1r + q * 1024 + lane * 8;
    } else {
        int q = pair - 56;
        int p = q >> 4, lp = q & 15, ct = lp >> 2, kc = lp & 3;
        src = Wcat; ldB = 320; col = p * 64 + ct * 16 + m; k0 = kc * 32 + g * 8;
        dst = pWcat + q * 1024 + lane * 8;
    }
    float e[8];
#pragma unroll
    for (int r = 0; r < 8; r++) e[r] = src[(size_t)(k0 + r) * ldB + col];
    union { bf16x8 v; unsigned u4[4]; } H, L;
#pragma unroll
    for (int j = 0; j < 4; j++) {
        unsigned b0 = __float_as_uint(e[2 * j]), b1 = __float_as_uint(e[2 * j + 1]);
        unsigned h0 = b0 & 0xFFFF0000u, h1 = b1 & 0xFFFF0000u;
        H.u4[j] = (h0 >> 16) | h1;
        float l0 = e[2 * j] - __uint_as_float(h0);
        float l1 = e[2 * j + 1] - __uint_as_float(h1);
        L.u4[j] = (__float_as_uint(l0) >> 16) | (__float_as_uint(l1) & 0xFFFF0000u);
    }
    *(bf16x8*)dst = H.v;
    *(bf16x8*)(dst + 512) = L.v;
}

// ============ MFMA GEMM: block = 4 waves x 16 rows = 64 rows, NCOL cols ============
// A loaded direct from global (fp32 -> bf16 hi/lo split in-register), B pre-packed frags.
// Layout invariance: A and B use the same k<->(laneGroup,reg) map, so result is exact
// for any HW k-permutation; C/D map col=lane&15, row=(lane>>4)*4+reg (m89-verified).
// ACT: 0=none, 2=relu(x+bias). No LDS, no barriers; wave-uniform row guard.
template <int KTOT, int NCOL, int ACT = 0>
__global__ __launch_bounds__(256) void k_mfma(const float* __restrict__ X, int ldX, int xmb,
                                              const short* __restrict__ Bpk, int bmb,
                                              float* __restrict__ Y, int ldY, size_t ymb,
                                              const float* __restrict__ bias, int biasmb) {
    constexpr int NKC = KTOT / 32;
    constexpr int NCT = NCOL / 16;
    const int tid = threadIdx.x;
    const int wid = tid >> 6, lane = tid & 63;
    const int m = lane & 15, g = lane >> 4;
    const int mb = blockIdx.y;
    const int rowbase = blockIdx.x * 64 + wid * 16;
    if (rowbase >= NN) return;  // NN % 16 == 0: per-wave all-or-nothing
    const float* Xm = X + (size_t)mb * xmb + (size_t)(rowbase + m) * ldX;
    const short* Bm = Bpk + (size_t)mb * bmb;

    f32x4 acc[NCT];
#pragma unroll
    for (int c = 0; c < NCT; c++) acc[c] = (f32x4){0.f, 0.f, 0.f, 0.f};

#pragma unroll
    for (int kc = 0; kc < NKC; kc++) {
        float4 v0 = *(const float4*)(Xm + kc * 32 + g * 8);
        float4 v1 = *(const float4*)(Xm + kc * 32 + g * 8 + 4);
        bf16x8 ah, al;
        split8(v0, v1, ah, al);
#pragma unroll
        for (int ct = 0; ct < NCT; ct++) {
            const short* bp = Bm + (size_t)(ct * NKC + kc) * 1024 + lane * 8;
            bf16x8 bh = *(const bf16x8*)bp;
            bf16x8 bl = *(const bf16x8*)(bp + 512);
            acc[ct] = __builtin_amdgcn_mfma_f32_16x16x32_bf16(ah, bh, acc[ct], 0, 0, 0);
            acc[ct] = __builtin_amdgcn_mfma_f32_16x16x32_bf16(al, bh, acc[ct], 0, 0, 0);
            acc[ct] = __builtin_amdgcn_mfma_f32_16x16x32_bf16(ah, bl, acc[ct], 0, 0, 0);
        }
    }

    float* Ym = Y + (size_t)mb * ymb + (size_t)(rowbase + g * 4) * ldY;
#pragma unroll
    for (int ct = 0; ct < NCT; ct++) {
        int col = ct * 16 + m;
        float bv = bias ? bias[mb * biasmb + col] : 0.f;
#pragma unroll
        for (int i = 0; i < 4; i++) {
            float o = acc[ct][i] + bv;
            if (ACT == 2) o = fmaxf(o, 0.f);
            Ym[(size_t)i * ldY + col] = o;
        }
    }
}

// ===== L1 basis-space gather: U[n][b][64] = sum_edges comp[r,b]*inv_cnt*x[src]; U[n][4][64]=x[n] =====
__global__ __launch_bounds__(256) void k_gagg1(const int* __restrict__ rp,
                                               const int* __restrict__ srcs2,
                                               const float* __restrict__ comp,
                                               const float* __restrict__ X,
                                               float* __restrict__ U) {
    __shared__ float4 sh_w[4][8];
    int wid = threadIdx.x >> 6, lane = threadIdx.x & 63;
    int n = blockIdx.x * 4 + wid;
    int rpv = (lane <= 8) ? rp[n * RR + lane] : 0;
    int nxt = __shfl(rpv, (lane + 1) & 63);
    if (lane < 8) {
        float inv = 1.f / (float)((nxt - rpv) > 0 ? (nxt - rpv) : 1);
        float4 c = *(const float4*)(comp + lane * 4);
        sh_w[wid][lane] = make_float4(c.x * inv, c.y * inv, c.z * inv, c.w * inv);
    }
    int q = lane & 15;
    int beg = rp[n * RR], end = rp[n * RR + RR];
    float4 a0 = make_float4(0.f, 0.f, 0.f, 0.f);
    float4 a1 = a0, a2 = a0, a3 = a0;
    int k = beg + (lane >> 4);
    for (; k + 4 < end; k += 8) {
        int key0 = srcs2[k], key1 = srcs2[k + 4];
        float4 w0 = sh_w[wid][key0 & 7], w1 = sh_w[wid][key1 & 7];
        float4 v0 = *(const float4*)(X + (size_t)(key0 >> 3) * 64 + q * 4);
        float4 v1 = *(const float4*)(X + (size_t)(key1 >> 3) * 64 + q * 4);
        fmacc(a0, v0, w0.x);
        fmacc(a1, v0, w0.y);
        fmacc(a2, v0, w0.z);
        fmacc(a3, v0, w0.w);
        fmacc(a0, v1, w1.x);
        fmacc(a1, v1, w1.y);
        fmacc(a2, v1, w1.z);
        fmacc(a3, v1, w1.w);
    }
    if (k < end) {
        int key0 = srcs2[k];
        float4 w0 = sh_w[wid][key0 & 7];
        float4 v0 = *(const float4*)(X + (size_t)(key0 >> 3) * 64 + q * 4);
        fmacc(a0, v0, w0.x);
        fmacc(a1, v0, w0.y);
        fmacc(a2, v0, w0.z);
        fmacc(a3, v0, w0.w);
    }
    red4(a0, 16); red4(a0, 32);
    red4(a1, 16); red4(a1, 32);
    red4(a2, 16); red4(a2, 32);
    red4(a3, 16); red4(a3, 32);
    if (lane < 16) {
        float* un = U + (size_t)n * 320;
        *(float4*)(un + 0 * 64 + q * 4) = a0;
        *(float4*)(un + 1 * 64 + q * 4) = a1;
        *(float4*)(un + 2 * 64 + q * 4) = a2;
        *(float4*)(un + 3 * 64 + q * 4) = a3;
        *(float4*)(un + 256 + q * 4) = *(const float4*)(X + (size_t)n * 64 + q * 4);
    }
}

// ===== skinny matvec: alds[n][j] = sum_c x1[n][c] * U1p[c*64+j], j<8 =====
__global__ __launch_bounds__(256) void k_alds1(const float* __restrict__ X,
                                               const float* __restrict__ U1p,
                                               float* __restrict__ alds) {
    __shared__ float sUT[8 * 68];  // sUT[j][c] = U1p[c*64 + j]
    int tid = threadIdx.x;
    for (int i = tid; i < 512; i += 256) {
        int j = i >> 6, c = i & 63;
        sUT[j * 68 + c] = U1p[c * 64 + j];
    }
    __syncthreads();
    int lane = tid & 63, wid = tid >> 6;
    int n = blockIdx.x * 32 + wid * 8 + (lane >> 3);
    int q = lane & 7;  // owns c-slice q*8..q*8+7
    float x[8];
    if (n < NN) {
        float4 v0 = *(const float4*)(X + (size_t)n * 64 + q * 8);
        float4 v1 = *(const float4*)(X + (size_t)n * 64 + q * 8 + 4);
        x[0] = v0.x; x[1] = v0.y; x[2] = v0.z; x[3] = v0.w;
        x[4] = v1.x; x[5] = v1.y; x[6] = v1.z; x[7] = v1.w;
    } else {
#pragma unroll
        for (int c = 0; c < 8; c++) x[c] = 0.f;
    }
    float al[8];
#pragma unroll
    for (int j = 0; j < 8; j++) {
        const float* u = &sUT[j * 68 + q * 8];
        float s = 0.f;
#pragma unroll
        for (int c = 0; c < 8; c++) s += x[c] * u[c];
        al[j] = s;
    }
#pragma unroll
    for (int m = 1; m < 8; m <<= 1)
#pragma unroll
        for (int j = 0; j < 8; j++) al[j] += __shfl_xor(al[j], m);
    if (n < NN) alds[(size_t)n * 8 + q] = al[q];
}

// ===== skinny final: out[n][c<16] = tanh(relu(0.25*sum_k msg2[n][k]*Wstk[k][c] + bg2[c])) =====
__global__ __launch_bounds__(256) void k_final(const float* __restrict__ Xm,
                                               const float* __restrict__ Wstk,
                                               const float* __restrict__ bg2,
                                               float* __restrict__ out) {
    __shared__ float sWT[16 * 132];  // sWT[c][k] = Wstk[k*64 + c]
    int tid = threadIdx.x;
    for (int i = tid; i < 2048; i += 256) {
        int c = i >> 7, k = i & 127;
        sWT[c * 132 + k] = Wstk[k * 64 + c];
    }
    __syncthreads();
    int lane = tid & 63, wid = tid >> 6;
    int n = blockIdx.x * 32 + wid * 8 + (lane >> 3);
    int q = lane & 7;  // owns k in {t*32 + q*4 + s}: conflict-free q*4 stride in LDS
    float x[16];
    if (n < NN) {
#pragma unroll
        for (int t = 0; t < 4; t++) {
            float4 v = *(const float4*)(Xm + (size_t)n * 128 + t * 32 + q * 4);
            x[t * 4 + 0] = v.x; x[t * 4 + 1] = v.y; x[t * 4 + 2] = v.z; x[t * 4 + 3] = v.w;
        }
    } else {
#pragma unroll
        for (int k = 0; k < 16; k++) x[k] = 0.f;
    }
    float al[16];
#pragma unroll
    for (int c = 0; c < 16; c++) {
        float s = 0.f;
#pragma unroll
        for (int t = 0; t < 4; t++) {
            const float* w = &sWT[c * 132 + t * 32 + q * 4];
            s += x[t * 4 + 0] * w[0] + x[t * 4 + 1] * w[1] + x[t * 4 + 2] * w[2] +
                 x[t * 4 + 3] * w[3];
        }
        al[c] = s;
    }
#pragma unroll
    for (int m = 1; m < 8; m <<= 1)
#pragma unroll
        for (int c = 0; c < 16; c++) al[c] += __shfl_xor(al[c], m);
    if (n < NN && q < 4) {
        float4 bv = *(const float4*)(bg2 + q * 4);
        float4 v;
        v.x = tanhf(fmaxf(0.25f * al[q * 4 + 0] + bv.x, 0.f));
        v.y = tanhf(fmaxf(0.25f * al[q * 4 + 1] + bv.y, 0.f));
        v.z = tanhf(fmaxf(0.25f * al[q * 4 + 2] + bv.z, 0.f));
        v.w = tanhf(fmaxf(0.25f * al[q * 4 + 3] + bv.w, 0.f));
        *(float4*)(out + (size_t)n * 16 + q * 4) = v;
    }
}

// ===== aggregate 2 + fused alds2: 8 edge-groups x 8 lanes; x3 stride 64; alds epilogue =====
__global__ __launch_bounds__(256) void k_agg2(const int* __restrict__ rp,
                                              const int* __restrict__ srcs2,
                                              const float* __restrict__ y,
                                              const float* __restrict__ bias,
                                              const float* __restrict__ U2p,
                                              float* __restrict__ x3,
                                              float* __restrict__ alds) {
    __shared__ float sh_inv[4][8];
    int wid = threadIdx.x >> 6, lane = threadIdx.x & 63;
    int n = blockIdx.x * 4 + wid;
    int rpv = (lane <= 8) ? rp[n * RR + lane] : 0;
    int nxt = __shfl(rpv, (lane + 1) & 63);
    if (lane < 8) sh_inv[wid][lane] = 1.f / (float)((nxt - rpv) > 0 ? (nxt - rpv) : 1);
    int q = lane & 7;
    int beg = rp[n * RR], end = rp[n * RR + RR];
    float4 acc = make_float4(0.f, 0.f, 0.f, 0.f);
    int k = beg + (lane >> 3);
    for (; k + 8 < end; k += 16) {
        int key0 = srcs2[k], key1 = srcs2[k + 8];
        int s0 = key0 >> 3, s1 = key1 >> 3;
        int g0 = key0 & 7, g1 = key1 & 7;
        float e0 = sh_inv[wid][g0], e1 = sh_inv[wid][g1];
        float4 v0 = *(const float4*)(y + ((size_t)(g0 >> 1) * NN + s0) * 64 + (g0 & 1) * 32 + q * 4);
        float4 v1 = *(const float4*)(y + ((size_t)(g1 >> 1) * NN + s1) * 64 + (g1 & 1) * 32 + q * 4);
        fmacc(acc, v0, e0);
        fmacc(acc, v1, e1);
    }
    if (k < end) {
        int key0 = srcs2[k];
        int s0 = key0 >> 3;
        int g0 = key0 & 7;
        float4 v0 = *(const float4*)(y + ((size_t)(g0 >> 1) * NN + s0) * 64 + (g0 & 1) * 32 + q * 4);
        fmacc(acc, v0, sh_inv[wid][g0]);
    }
    red4(acc, 8);
    red4(acc, 16);
    red4(acc, 32);
    if (lane < 8) {
        float4 prev = *(const float4*)(x3 + (size_t)n * 64 + q * 4);
        float4 b = *(const float4*)(bias + q * 4);
        float4 v;
        v.x = fmaxf(prev.x + acc.x + b.x, 0.f);
        v.y = fmaxf(prev.y + acc.y + b.y, 0.f);
        v.z = fmaxf(prev.z + acc.z + b.z, 0.f);
        v.w = fmaxf(prev.w + acc.w + b.w, 0.f);
        *(float4*)(x3 + (size_t)n * 64 + q * 4) = v;
        // fused alds2: al[j] = sum_c x3[n][c] * U2p[c*64+j], c = q*4..q*4+3 per lane
        float al[8];
#pragma unroll
        for (int j = 0; j < 8; j++) {
            al[j] = fmaf(v.x, U2p[(q * 4 + 0) * 64 + j],
                    fmaf(v.y, U2p[(q * 4 + 1) * 64 + j],
                    fmaf(v.z, U2p[(q * 4 + 2) * 64 + j],
                         v.w * U2p[(q * 4 + 3) * 64 + j])));
        }
#pragma unroll
        for (int m = 1; m < 8; m <<= 1) {
#pragma unroll
            for (int j = 0; j < 8; j++) al[j] += __shfl_xor(al[j], m);
        }
        alds[n * 8 + q] = al[q];
    }
}

// ===== fused GAT aggregation in input space; alds[n][8] = (als[0..3], ald[0..3]) =====
template <int F, int LDX = F>
__global__ __launch_bounds__(256) void k_gatx(const int* __restrict__ rp,
                                              const int* __restrict__ srcs2,
                                              const float* __restrict__ alds,
                                              const float* __restrict__ X,
                                              float* __restrict__ msg) {
    constexpr int G = F / 4;    // lanes per edge-group (16 or 8)
    constexpr int NG = 64 / G;  // groups per wave (4 or 8)
    int wid = threadIdx.x >> 6, lane = threadIdx.x & 63;
    int n = blockIdx.x * 4 + wid;
    if (n >= NN) return;
    int g = lane / G, q = lane % G;
    float4 ald4 = *(const float4*)(alds + n * 8 + 4);
    float4 acc0 = make_float4(0.f, 0.f, 0.f, 0.f);
    float4 acc1 = acc0, acc2 = acc0, acc3 = acc0;
    float4 z = make_float4(0.f, 0.f, 0.f, 0.f);
    if (g == 0) {  // self loop
        float4 a4 = *(const float4*)(alds + n * 8);
        float4 xv = *(const float4*)(X + (size_t)n * LDX + q * 4);
        float p0 = __expf(leaky(a4.x + ald4.x));
        float p1 = __expf(leaky(a4.y + ald4.y));
        float p2 = __expf(leaky(a4.z + ald4.z));
        float p3 = __expf(leaky(a4.w + ald4.w));
        z = make_float4(p0, p1, p2, p3);
        fmacc(acc0, xv, p0);
        fmacc(acc1, xv, p1);
        fmacc(acc2, xv, p2);
        fmacc(acc3, xv, p3);
    }
    int beg = rp[n * RR], end = rp[n * RR + RR];
    int k = beg + g;
    for (; k + NG < end; k += 2 * NG) {
        int s0 = srcs2[k] >> 3, s1 = srcs2[k + NG] >> 3;
        float4 a0 = *(const float4*)(alds + s0 * 8);
        float4 a1 = *(const float4*)(alds + s1 * 8);
        float4 x0 = *(const float4*)(X + (size_t)s0 * LDX + q * 4);
        float4 x1v = *(const float4*)(X + (size_t)s1 * LDX + q * 4);
        float p00 = __expf(leaky(a0.x + ald4.x)), p01 = __expf(leaky(a0.y + ald4.y));
        float p02 = __expf(leaky(a0.z + ald4.z)), p03 = __expf(leaky(a0.w + ald4.w));
        float p10 = __expf(leaky(a1.x + ald4.x)), p11 = __expf(leaky(a1.y + ald4.y));
        float p12 = __expf(leaky(a1.z + ald4.z)), p13 = __expf(leaky(a1.w + ald4.w));
        z.x += p00 + p10;
        z.y += p01 + p11;
        z.z += p02 + p12;
        z.w += p03 + p13;
        fmacc(acc0, x0, p00);
        fmacc(acc1, x0, p01);
        fmacc(acc2, x0, p02);
        fmacc(acc3, x0, p03);
        fmacc(acc0, x1v, p10);
        fmacc(acc1, x1v, p11);
        fmacc(acc2, x1v, p12);
        fmacc(acc3, x1v, p13);
    }
    if (k < end) {
        int s0 = srcs2[k] >> 3;
        float4 a0 = *(const float4*)(alds + s0 * 8);
        float4 x0 = *(const float4*)(X + (size_t)s0 * LDX + q * 4);
        float p00 = __expf(leaky(a0.x + ald4.x)), p01 = __expf(leaky(a0.y + ald4.y));
        float p02 = __expf(leaky(a0.z + ald4.z)), p03 = __expf(leaky(a0.w + ald4.w));
        z.x += p00;
        z.y += p01;
        z.z += p02;
        z.w += p03;
        fmacc(acc0, x0, p00);
        fmacc(acc1, x0, p01);
        fmacc(acc2, x0, p02);
        fmacc(acc3, x0, p03);
    }
#pragma unroll
    for (int m = G; m < 64; m <<= 1) {
        red4(acc0, m);
        red4(acc1, m);
        red4(acc2, m);
        red4(acc3, m);
        red4(z, m);
    }
    if (g == 0) {
        float4 iz = make_float4(1.f / z.x, 1.f / z.y, 1.f / z.z, 1.f / z.w);
        float* mp = msg + (size_t)n * 4 * F + q * 4;
        *(float4*)(mp + 0 * F) = make_float4(acc0.x * iz.x, acc0.y * iz.x, acc0.z * iz.x, acc0.w * iz.x);
        *(float4*)(mp + 1 * F) = make_float4(acc1.x * iz.y, acc1.y * iz.y, acc1.z * iz.y, acc1.w * iz.y);
        *(float4*)(mp + 2 * F) = make_float4(acc2.x * iz.z, acc2.y * iz.z, acc2.z * iz.z, acc2.w * iz.z);
        *(float4*)(mp + 3 * F) = make_float4(acc3.x * iz.w, acc3.y * iz.w, acc3.z * iz.w, acc3.w * iz.w);
    }
}

extern "C" void kernel_launch(void* const* d_in, const int* in_sizes, int n_in,
                              void* d_out, int out_size, void* d_ws, size_t ws_size,
                              hipStream_t stream) {
    const float* x      = (const float*)d_in[0];
    const int*   ei     = (const int*)d_in[1];
    const int*   et     = (const int*)d_in[2];
    const float* basis1 = (const float*)d_in[3];
    const float* comp1  = (const float*)d_in[4];
    const float* root1  = (const float*)d_in[5];
    const float* brg1   = (const float*)d_in[6];
    const float* wg1    = (const float*)d_in[7];
    const float* asrc1  = (const float*)d_in[8];
    const float* adst1  = (const float*)d_in[9];
    const float* bg1    = (const float*)d_in[10];
    const float* basis2 = (const float*)d_in[11];
    const float* comp2  = (const float*)d_in[12];
    const float* root2  = (const float*)d_in[13];
    const float* brg2   = (const float*)d_in[14];
    const float* wg2    = (const float*)d_in[15];
    const float* asrc2  = (const float*)d_in[16];
    const float* adst2  = (const float*)d_in[17];
    const float* bg2    = (const float*)d_in[18];
    const int* src = ei;
    const int* dst = ei + EE;
    float* out = (float*)d_out;

    // ---- int region ----
    int* wsi = (int*)d_ws;
    size_t ioff = 0;
    auto ialloc = [&](size_t n) { int* p = wsi + ioff; ioff += (n + 3) & ~(size_t)3; return p; };
    int* cnt2 = ialloc(SEGS);  // reused as fill cursors (wo)
    int* rp   = ialloc(SEGS + 1);
    int* bsum = ialloc(2048);
    int* srcs2 = ialloc(EE);
    int* wo = cnt2;
    // ---- float region ----
    float* wsf = (float*)(wsi + ioff);
    size_t total_f = (ws_size - ioff * sizeof(int)) / sizeof(float);
    size_t P_f = (size_t)NN * 320;
    size_t need_f = P_f + (size_t)NN * 128
                  + 40960 + 20480 + 16384 + 8192 + 4096 + 2048
                  + (size_t)NN * 8
                  + 20480 + 8192 + 40960 + 64;  // bf16 hi/lo packed weights
    if (total_f < need_f) return;  // loud fail: output stays zero
    size_t foff = 0;
    auto falloc = [&](size_t n) { float* p = wsf + foff; foff += (n + 3) & ~(size_t)3; return p; };
    float* P      = falloc(P_f);
    float* x2     = falloc((size_t)NN * 128);
    float* Wcat2e = falloc(40960);           // [128][320]: root2(pad) | W_r pairs
    float* Wb1    = falloc(20480);           // [320][64]: basis1 rows | root1 rows
    float* wg1r   = falloc(16384);
    float* Wstk   = falloc(8192);
    float* U1p    = falloc(4096);
    float* U2p    = falloc(2048);
    float* alds   = falloc((size_t)NN * 8);
    short* Wb1pk  = (short*)falloc(20480);   // 40 pairs x 1024 shorts
    short* wg1rpk = (short*)falloc(8192);    // 16 pairs
    short* Wcatpk = (short*)falloc(40960);   // 80 pairs (5 panels x 16)
    float* Ubuf = P;                  // L1 basis-gather output [n][320]
    float* x1   = x2 + (size_t)NN * 64;  // dead before msg1-gemm overwrites x2 region
    float* msg1 = P;                  // [n][4][64] (U dead after u-gemm)
    float* x3   = P;                  // stride 64 = L3 panel 0 (root); cols 32-63 zero pad
    float* ybuf3 = P + (size_t)NN * 64;  // L3 panels 1-4 (relation pairs)
    float* msg2 = P + (size_t)NN * 64;   // [n][4][32] (ybuf3 dead after agg2; disjoint from x3)

    const int EB = (EE + 255) / 256;
    const int NB4 = (NN + 3) / 4;    // NN % 4 == 0 -> exact
    const int NB32 = (NN + 31) / 32; // 1563 (skinny matvec blocks, 32 nodes each)

    // ---- CSR build ----
    hipMemsetAsync(cnt2, 0, SEGS * sizeof(int), stream);
    k_count2<<<EB, 256, 0, stream>>>(dst, et, cnt2);
    k_scanA<<<NBLK, 256, 0, stream>>>(cnt2, rp, bsum);
    k_scanB<<<1, 256, 0, stream>>>(bsum);
    k_scanC<<<NBLK, 256, 0, stream>>>(rp, bsum, wo);
    k_fill<<<EB, 256, 0, stream>>>(src, dst, et, wo, srcs2);
    k_prep<<<(92160 + 255) / 256, 256, 0, stream>>>(
        wg1, wg2, root1, root2, basis1, basis2, comp2, asrc1, adst1, asrc2, adst2,
        Wcat2e, wg1r, Wstk, U1p, U2p, Wb1);
    k_pack<<<34, 256, 0, stream>>>(Wb1, wg1r, Wcat2e, Wb1pk, wg1rpk, Wcatpk);

    // ---- layer 1: RGCN(64->64)+relu via basis-space gather + one K=320 MFMA GEMM ----
    k_gagg1<<<NB4, 256, 0, stream>>>(rp, srcs2, comp1, x, Ubuf);
    k_mfma<320, 64, 2><<<dim3(NTW, 1), 256, 0, stream>>>(Ubuf, 320, 0, Wb1pk, 0,
                                                         x1, 64, 0, brg1, 0);

    // ---- layer 2: GAT(64 -> 4x32 concat), aggregated in input space ----
    k_alds1<<<NB32, 256, 0, stream>>>(x1, U1p, alds);
    k_gatx<64><<<NB4, 256, 0, stream>>>(rp, srcs2, alds, x1, msg1);
    k_mfma<64, 32, 0><<<dim3(NTW, 4), 256, 0, stream>>>(msg1, 256, 64, wg1rpk, 4096,
                                                        x2, 128, 32, bg1, 32);

    // ---- layer 3: RGCN(128->32)+relu; 5 panels (root + 4 rel pairs) via MFMA ----
    k_mfma<128, 64, 0><<<dim3(NTW, 5), 256, 0, stream>>>(x2, 128, 0, Wcatpk, 16384,
                                                         P, 64, (size_t)NN * 64, nullptr, 0);
    k_agg2<<<NB4, 256, 0, stream>>>(rp, srcs2, ybuf3, brg2, U2p, x3, alds);

    // ---- layer 4: GAT(32 -> 4x16, mean heads) + relu + tanh (alds fused into agg2) ----
    k_gatx<32, 64><<<NB4, 256, 0, stream>>>(rp, srcs2, alds, x3, msg2);
    k_final<<<NB32, 256, 0, stream>>>(msg2, Wstk, bg2, out);
}

// Round 5
// 459.429 us; speedup vs baseline: 1.1808x; 1.0328x over previous
//
#include <hip/hip_runtime.h>
#include <math.h>

#define NN 50000
#define EE 800000
#define RR 8
#define SLOPE 0.2f
#define SEGS (NN * RR)            /* 400000 per-(node,relation) segments */
#define NBLK ((SEGS + 255) / 256) /* 1563 scan blocks */
#define NTW ((NN + 63) / 64)      /* 782 mfma row-tiles (64 rows each) */

typedef __attribute__((ext_vector_type(8))) short bf16x8;
typedef __attribute__((ext_vector_type(4))) float f32x4;
typedef _Float16 f16;
typedef __attribute__((ext_vector_type(4))) _Float16 h4;
typedef __attribute__((ext_vector_type(8))) _Float16 h8;

__device__ __forceinline__ float leaky(float v) { return v >= 0.f ? v : SLOPE * v; }

__device__ __forceinline__ void fmacc(float4& a, const float4& v, float p) {
    a.x = fmaf(v.x, p, a.x);
    a.y = fmaf(v.y, p, a.y);
    a.z = fmaf(v.z, p, a.z);
    a.w = fmaf(v.w, p, a.w);
}

__device__ __forceinline__ void red4(float4& a, int m) {
    a.x += __shfl_xor(a.x, m);
    a.y += __shfl_xor(a.y, m);
    a.z += __shfl_xor(a.z, m);
    a.w += __shfl_xor(a.w, m);
}

__device__ __forceinline__ float4 h4tof4(h4 t) {
    return make_float4((float)t.x, (float)t.y, (float)t.z, (float)t.w);
}

// split 8 fp32 -> bf16 hi (truncate) + bf16 lo (truncate of exact residual).
// 3-term mfma (AhBh+AlBh+AhBl) then has ~2^-17 relative error (fp32-grade here).
__device__ __forceinline__ void split8(const float4& v0, const float4& v1,
                                       bf16x8& hi, bf16x8& lo) {
    float e[8] = {v0.x, v0.y, v0.z, v0.w, v1.x, v1.y, v1.z, v1.w};
    union { bf16x8 v; unsigned u[4]; } H, L;
#pragma unroll
    for (int j = 0; j < 4; j++) {
        unsigned b0 = __float_as_uint(e[2 * j]), b1 = __float_as_uint(e[2 * j + 1]);
        unsigned h0 = b0 & 0xFFFF0000u, h1 = b1 & 0xFFFF0000u;
        H.u[j] = (h0 >> 16) | h1;
        float l0 = e[2 * j] - __uint_as_float(h0);
        float l1 = e[2 * j + 1] - __uint_as_float(h1);
        L.u[j] = (__float_as_uint(l0) >> 16) | (__float_as_uint(l1) & 0xFFFF0000u);
    }
    hi = H.v;
    lo = L.v;
}

// ============================ CSR build ============================
__global__ void k_count2(const int* __restrict__ dst, const int* __restrict__ et,
                         int* __restrict__ cnt2) {
    int e = blockIdx.x * 256 + threadIdx.x;
    if (e < EE) atomicAdd(&cnt2[dst[e] * RR + et[e]], 1);
}

__global__ void k_scanA(const int* __restrict__ cnt2, int* __restrict__ rp,
                        int* __restrict__ bsum) {
    __shared__ int sh[256];
    int t = threadIdx.x;
    int i = blockIdx.x * 256 + t;
    int v = (i < SEGS) ? cnt2[i] : 0;
    sh[t] = v;
    __syncthreads();
    for (int off = 1; off < 256; off <<= 1) {
        int u = (t >= off) ? sh[t - off] : 0;
        __syncthreads();
        sh[t] += u;
        __syncthreads();
    }
    if (i < SEGS) rp[i] = sh[t] - v;
    if (t == 255) bsum[blockIdx.x] = sh[255];
}

__global__ void k_scanB(int* __restrict__ bsum) {
    __shared__ int sh[256];
    int t = threadIdx.x;
    int loc[8];
    int s = 0;
#pragma unroll
    for (int i = 0; i < 8; i++) {
        int idx = t * 8 + i;
        int v = (idx < NBLK) ? bsum[idx] : 0;
        loc[i] = v;
        s += v;
    }
    sh[t] = s;
    __syncthreads();
    for (int off = 1; off < 256; off <<= 1) {
        int u = (t >= off) ? sh[t - off] : 0;
        __syncthreads();
        sh[t] += u;
        __syncthreads();
    }
    int run = sh[t] - s;
#pragma unroll
    for (int i = 0; i < 8; i++) {
        int idx = t * 8 + i;
        if (idx < NBLK) {
            int v = loc[i];
            bsum[idx] = run;
            run += v;
        }
    }
}

__global__ void k_scanC(int* __restrict__ rp, const int* __restrict__ bsum,
                        int* __restrict__ wo) {
    int i = blockIdx.x * 256 + threadIdx.x;
    if (i < SEGS) {
        int v = rp[i] + bsum[blockIdx.x];
        rp[i] = v;
        wo[i] = v;
    }
    if (i == 0) rp[SEGS] = EE;
}

// fill packed keys: srcs2[pos] = src*8 + relation (single scattered store per edge)
__global__ void k_fill(const int* __restrict__ src, const int* __restrict__ dst,
                       const int* __restrict__ et, int* __restrict__ wo,
                       int* __restrict__ srcs2) {
    int e = blockIdx.x * 256 + threadIdx.x;
    if (e >= EE) return;
    int r = et[e];
    int seg = dst[e] * RR + r;
    int pos = atomicAdd(&wo[seg], 1);
    srcs2[pos] = (src[e] << 3) | r;
}

// ==== prep (merged): padded weights, logit projections, stacked Wb1, Wcat2e compose ====
__global__ void k_prep(const float* __restrict__ wg1, const float* __restrict__ wg2,
                       const float* __restrict__ root1, const float* __restrict__ root2,
                       const float* __restrict__ basis1, const float* __restrict__ basis2,
                       const float* __restrict__ comp2,
                       const float* __restrict__ asrc1, const float* __restrict__ adst1,
                       const float* __restrict__ asrc2, const float* __restrict__ adst2,
                       float* __restrict__ Wcat2e, float* __restrict__ wg1r,
                       float* __restrict__ Wstk, float* __restrict__ U1p,
                       float* __restrict__ U2p, float* __restrict__ Wb1) {
    int idx = blockIdx.x * 256 + threadIdx.x;
    if (idx < 16384) {  // wg1r[h][k][c] (c<32 valid)
        int h = idx >> 12, kc = idx & 4095;
        int k = kc >> 6, c = kc & 63;
        wg1r[idx] = (c < 32) ? wg1[k * 128 + h * 32 + c] : 0.f;
    } else if (idx < 24576) {  // Wstk[h*32+k][c] = wg2[k][h*16+c] (c<16 valid)
        int j = idx - 16384;
        int row = j >> 6, c = j & 63;
        int h = row >> 5, k = row & 31;
        Wstk[j] = (c < 16) ? wg2[k * 64 + h * 16 + c] : 0.f;
    } else if (idx < 32768) {  // Wcat2e root block: [128][col 0-63] = root2 zero-padded
        int j = idx - 24576;
        int k = j >> 6, c = j & 63;
        Wcat2e[k * 320 + c] = (c < 32) ? root2[k * 32 + c] : 0.f;
    } else if (idx < 36864) {  // U1p[k][j]: j<4 src head j, 4<=j<8 dst head j-4, else 0
        int j0 = idx - 32768;
        int k = j0 >> 6, j = j0 & 63;
        float s = 0.f;
        if (j < 8) {
            int h = j & 3;
            const float* a = (j < 4) ? asrc1 : adst1;
            for (int c = 0; c < 32; c++) s += wg1[k * 128 + h * 32 + c] * a[h * 32 + c];
        }
        U1p[j0] = s;
    } else if (idx < 38912) {  // U2p[k][j]
        int j0 = idx - 36864;
        int k = j0 >> 6, j = j0 & 63;
        float s = 0.f;
        if (j < 8) {
            int h = j & 3;
            const float* a = (j < 4) ? asrc2 : adst2;
            for (int c = 0; c < 16; c++) s += wg2[k * 64 + h * 16 + c] * a[h * 16 + c];
        }
        U2p[j0] = s;
    } else if (idx < 55296) {  // Wb1 rows 0-255 = basis1 [4][64][64] flat copy
        Wb1[idx - 38912] = basis1[idx - 38912];
    } else if (idx < 59392) {  // Wb1 rows 256-319 = root1
        Wb1[idx - 38912] = root1[idx - 55296];
    } else if (idx < 92160) {  // Wcat2e basis-composed block: [128][col 64-319]
        int j = idx - 59392;
        int i = j >> 8, rc = j & 255;
        int r = rc >> 5, o = rc & 31;
        float acc = 0.f;
#pragma unroll
        for (int b = 0; b < 4; b++) acc += comp2[r * 4 + b] * basis2[b * 4096 + i * 32 + o];
        Wcat2e[i * 320 + 64 + rc] = acc;
    }
}

// ==== pack weights into bf16 hi/lo MFMA fragment order ====
// frag element r of lane (g=lane>>4, m=lane&15): B[k = kc*32 + g*8 + r][col = ct*16 + m].
// pair layout: [pairIdx = ct*NKC + kc][hi:0/lo:1][lane][8] -> 1024 shorts per pair.
__global__ void k_pack(const float* __restrict__ Wb1, const float* __restrict__ wg1r,
                       const float* __restrict__ Wcat, short* __restrict__ pWb1,
                       short* __restrict__ pwg1r, short* __restrict__ pWcat) {
    int u = blockIdx.x * 256 + threadIdx.x;
    int lane = u & 63, pair = u >> 6;
    if (pair >= 136) return;
    int m = lane & 15, g = lane >> 4;
    const float* src;
    int ldB, col, k0;
    short* dst;
    if (pair < 40) {
        int ct = pair / 10, kc = pair % 10;
        src = Wb1; ldB = 64; col = ct * 16 + m; k0 = kc * 32 + g * 8;
        dst = pWb1 + pair * 1024 + lane * 8;
    } else if (pair < 56) {
        int q = pair - 40;
        int h = q >> 2, lp = q & 3, ct = lp >> 1, kc = lp & 1;
        src = wg1r + h * 4096; ldB = 64; col = ct * 16 + m; k0 = kc * 32 + g * 8;
        dst = pwg1r + q * 1024 + lane * 8;
    } else {
        int q = pair - 56;
        int p = q >> 4, lp = q & 15, ct = lp >> 2, kc = lp & 3;
        src = Wcat; ldB = 320; col = p * 64 + ct * 16 + m; k0 = kc * 32 + g * 8;
        dst = pWcat + q * 1024 + lane * 8;
    }
    float e[8];
#pragma unroll
    for (int r = 0; r < 8; r++) e[r] = src[(size_t)(k0 + r) * ldB + col];
    union { bf16x8 v; unsigned u4[4]; } H, L;
#pragma unroll
    for (int j = 0; j < 4; j++) {
        unsigned b0 = __float_as_uint(e[2 * j]), b1 = __float_as_uint(e[2 * j + 1]);
        unsigned h0 = b0 & 0xFFFF0000u, h1 = b1 & 0xFFFF0000u;
        H.u4[j] = (h0 >> 16) | h1;
        float l0 = e[2 * j] - __uint_as_float(h0);
        float l1 = e[2 * j + 1] - __uint_as_float(h1);
        L.u4[j] = (__float_as_uint(l0) >> 16) | (__float_as_uint(l1) & 0xFFFF0000u);
    }
    *(bf16x8*)dst = H.v;
    *(bf16x8*)(dst + 512) = L.v;
}

// ============ MFMA GEMM: block = 4 waves x 16 rows = 64 rows, NCOL cols ============
// OUTH=1: write Y as fp16 (ldY/ymb in f16 elements). ACT: 0=none, 2=relu(x+bias).
template <int KTOT, int NCOL, int ACT = 0, int OUTH = 0>
__global__ __launch_bounds__(256) void k_mfma(const float* __restrict__ X, int ldX, int xmb,
                                              const short* __restrict__ Bpk, int bmb,
                                              float* __restrict__ Y, int ldY, size_t ymb,
                                              const float* __restrict__ bias, int biasmb) {
    constexpr int NKC = KTOT / 32;
    constexpr int NCT = NCOL / 16;
    const int tid = threadIdx.x;
    const int wid = tid >> 6, lane = tid & 63;
    const int m = lane & 15, g = lane >> 4;
    const int mb = blockIdx.y;
    const int rowbase = blockIdx.x * 64 + wid * 16;
    if (rowbase >= NN) return;  // NN % 16 == 0: per-wave all-or-nothing
    const float* Xm = X + (size_t)mb * xmb + (size_t)(rowbase + m) * ldX;
    const short* Bm = Bpk + (size_t)mb * bmb;

    f32x4 acc[NCT];
#pragma unroll
    for (int c = 0; c < NCT; c++) acc[c] = (f32x4){0.f, 0.f, 0.f, 0.f};

#pragma unroll
    for (int kc = 0; kc < NKC; kc++) {
        float4 v0 = *(const float4*)(Xm + kc * 32 + g * 8);
        float4 v1 = *(const float4*)(Xm + kc * 32 + g * 8 + 4);
        bf16x8 ah, al;
        split8(v0, v1, ah, al);
#pragma unroll
        for (int ct = 0; ct < NCT; ct++) {
            const short* bp = Bm + (size_t)(ct * NKC + kc) * 1024 + lane * 8;
            bf16x8 bh = *(const bf16x8*)bp;
            bf16x8 bl = *(const bf16x8*)(bp + 512);
            acc[ct] = __builtin_amdgcn_mfma_f32_16x16x32_bf16(ah, bh, acc[ct], 0, 0, 0);
            acc[ct] = __builtin_amdgcn_mfma_f32_16x16x32_bf16(al, bh, acc[ct], 0, 0, 0);
            acc[ct] = __builtin_amdgcn_mfma_f32_16x16x32_bf16(ah, bl, acc[ct], 0, 0, 0);
        }
    }

#pragma unroll
    for (int ct = 0; ct < NCT; ct++) {
        int col = ct * 16 + m;
        float bv = bias ? bias[mb * biasmb + col] : 0.f;
#pragma unroll
        for (int i = 0; i < 4; i++) {
            float o = acc[ct][i] + bv;
            if (ACT == 2) o = fmaxf(o, 0.f);
            if (OUTH) {
                f16* Yh = (f16*)Y;
                Yh[(size_t)mb * ymb + (size_t)(rowbase + g * 4 + i) * ldY + col] = (f16)o;
            } else {
                Y[(size_t)mb * ymb + (size_t)(rowbase + g * 4 + i) * ldY + col] = o;
            }
        }
    }
}

// ===== L1 basis-space gather: U[n][b][64] = sum_edges comp[r,b]*inv_cnt*x[src]; U[n][4][64]=x[n] =====
__global__ __launch_bounds__(256) void k_gagg1(const int* __restrict__ rp,
                                               const int* __restrict__ srcs2,
                                               const float* __restrict__ comp,
                                               const float* __restrict__ X,
                                               float* __restrict__ U) {
    __shared__ float4 sh_w[4][8];
    int wid = threadIdx.x >> 6, lane = threadIdx.x & 63;
    int n = blockIdx.x * 4 + wid;
    int rpv = (lane <= 8) ? rp[n * RR + lane] : 0;
    int nxt = __shfl(rpv, (lane + 1) & 63);
    if (lane < 8) {
        float inv = 1.f / (float)((nxt - rpv) > 0 ? (nxt - rpv) : 1);
        float4 c = *(const float4*)(comp + lane * 4);
        sh_w[wid][lane] = make_float4(c.x * inv, c.y * inv, c.z * inv, c.w * inv);
    }
    int q = lane & 15;
    int beg = rp[n * RR], end = rp[n * RR + RR];
    float4 a0 = make_float4(0.f, 0.f, 0.f, 0.f);
    float4 a1 = a0, a2 = a0, a3 = a0;
    int k = beg + (lane >> 4);
    for (; k + 4 < end; k += 8) {
        int key0 = srcs2[k], key1 = srcs2[k + 4];
        float4 w0 = sh_w[wid][key0 & 7], w1 = sh_w[wid][key1 & 7];
        float4 v0 = *(const float4*)(X + (size_t)(key0 >> 3) * 64 + q * 4);
        float4 v1 = *(const float4*)(X + (size_t)(key1 >> 3) * 64 + q * 4);
        fmacc(a0, v0, w0.x);
        fmacc(a1, v0, w0.y);
        fmacc(a2, v0, w0.z);
        fmacc(a3, v0, w0.w);
        fmacc(a0, v1, w1.x);
        fmacc(a1, v1, w1.y);
        fmacc(a2, v1, w1.z);
        fmacc(a3, v1, w1.w);
    }
    if (k < end) {
        int key0 = srcs2[k];
        float4 w0 = sh_w[wid][key0 & 7];
        float4 v0 = *(const float4*)(X + (size_t)(key0 >> 3) * 64 + q * 4);
        fmacc(a0, v0, w0.x);
        fmacc(a1, v0, w0.y);
        fmacc(a2, v0, w0.z);
        fmacc(a3, v0, w0.w);
    }
    red4(a0, 16); red4(a0, 32);
    red4(a1, 16); red4(a1, 32);
    red4(a2, 16); red4(a2, 32);
    red4(a3, 16); red4(a3, 32);
    if (lane < 16) {
        float* un = U + (size_t)n * 320;
        *(float4*)(un + 0 * 64 + q * 4) = a0;
        *(float4*)(un + 1 * 64 + q * 4) = a1;
        *(float4*)(un + 2 * 64 + q * 4) = a2;
        *(float4*)(un + 3 * 64 + q * 4) = a3;
        *(float4*)(un + 256 + q * 4) = *(const float4*)(X + (size_t)n * 64 + q * 4);
    }
}

// ===== skinny matvec + x1h emit: alds[n][j] = sum_c x1[n][c]*U1p[c*64+j]; x1h = fp16(x1) =====
__global__ __launch_bounds__(256) void k_alds1(const float* __restrict__ X,
                                               const float* __restrict__ U1p,
                                               float* __restrict__ alds,
                                               f16* __restrict__ x1h) {
    __shared__ float sUT[8 * 68];  // sUT[j][c] = U1p[c*64 + j]
    int tid = threadIdx.x;
    for (int i = tid; i < 512; i += 256) {
        int j = i >> 6, c = i & 63;
        sUT[j * 68 + c] = U1p[c * 64 + j];
    }
    __syncthreads();
    int lane = tid & 63, wid = tid >> 6;
    int n = blockIdx.x * 32 + wid * 8 + (lane >> 3);
    int q = lane & 7;  // owns c-slice q*8..q*8+7
    float x[8];
    if (n < NN) {
        float4 v0 = *(const float4*)(X + (size_t)n * 64 + q * 8);
        float4 v1 = *(const float4*)(X + (size_t)n * 64 + q * 8 + 4);
        x[0] = v0.x; x[1] = v0.y; x[2] = v0.z; x[3] = v0.w;
        x[4] = v1.x; x[5] = v1.y; x[6] = v1.z; x[7] = v1.w;
        h8 hv;
#pragma unroll
        for (int c = 0; c < 8; c++) hv[c] = (f16)x[c];
        *(h8*)(x1h + (size_t)n * 64 + q * 8) = hv;
    } else {
#pragma unroll
        for (int c = 0; c < 8; c++) x[c] = 0.f;
    }
    float al[8];
#pragma unroll
    for (int j = 0; j < 8; j++) {
        const float* u = &sUT[j * 68 + q * 8];
        float s = 0.f;
#pragma unroll
        for (int c = 0; c < 8; c++) s += x[c] * u[c];
        al[j] = s;
    }
#pragma unroll
    for (int m = 1; m < 8; m <<= 1)
#pragma unroll
        for (int j = 0; j < 8; j++) al[j] += __shfl_xor(al[j], m);
    if (n < NN) alds[(size_t)n * 8 + q] = al[q];
}

// ===== skinny final: out[n][c<16] = tanh(relu(0.25*sum_k msg2[n][k]*Wstk[k][c] + bg2[c])) =====
__global__ __launch_bounds__(256) void k_final(const float* __restrict__ Xm,
                                               const float* __restrict__ Wstk,
                                               const float* __restrict__ bg2,
                                               float* __restrict__ out) {
    __shared__ float sWT[16 * 132];  // sWT[c][k] = Wstk[k*64 + c]
    int tid = threadIdx.x;
    for (int i = tid; i < 2048; i += 256) {
        int c = i >> 7, k = i & 127;
        sWT[c * 132 + k] = Wstk[k * 64 + c];
    }
    __syncthreads();
    int lane = tid & 63, wid = tid >> 6;
    int n = blockIdx.x * 32 + wid * 8 + (lane >> 3);
    int q = lane & 7;  // owns k in {t*32 + q*4 + s}: conflict-free q*4 stride in LDS
    float x[16];
    if (n < NN) {
#pragma unroll
        for (int t = 0; t < 4; t++) {
            float4 v = *(const float4*)(Xm + (size_t)n * 128 + t * 32 + q * 4);
            x[t * 4 + 0] = v.x; x[t * 4 + 1] = v.y; x[t * 4 + 2] = v.z; x[t * 4 + 3] = v.w;
        }
    } else {
#pragma unroll
        for (int k = 0; k < 16; k++) x[k] = 0.f;
    }
    float al[16];
#pragma unroll
    for (int c = 0; c < 16; c++) {
        float s = 0.f;
#pragma unroll
        for (int t = 0; t < 4; t++) {
            const float* w = &sWT[c * 132 + t * 32 + q * 4];
            s += x[t * 4 + 0] * w[0] + x[t * 4 + 1] * w[1] + x[t * 4 + 2] * w[2] +
                 x[t * 4 + 3] * w[3];
        }
        al[c] = s;
    }
#pragma unroll
    for (int m = 1; m < 8; m <<= 1)
#pragma unroll
        for (int c = 0; c < 16; c++) al[c] += __shfl_xor(al[c], m);
    if (n < NN && q < 4) {
        float4 bv = *(const float4*)(bg2 + q * 4);
        float4 v;
        v.x = tanhf(fmaxf(0.25f * al[q * 4 + 0] + bv.x, 0.f));
        v.y = tanhf(fmaxf(0.25f * al[q * 4 + 1] + bv.y, 0.f));
        v.z = tanhf(fmaxf(0.25f * al[q * 4 + 2] + bv.z, 0.f));
        v.w = tanhf(fmaxf(0.25f * al[q * 4 + 3] + bv.w, 0.f));
        *(float4*)(out + (size_t)n * 16 + q * 4) = v;
    }
}

// ===== aggregate 2 + fused alds2: y gathered as fp16; emits x3h (fp16, stride 32) =====
__global__ __launch_bounds__(256) void k_agg2(const int* __restrict__ rp,
                                              const int* __restrict__ srcs2,
                                              const f16* __restrict__ y,
                                              const float* __restrict__ bias,
                                              const float* __restrict__ U2p,
                                              const float* __restrict__ x3prev,
                                              f16* __restrict__ x3h,
                                              float* __restrict__ alds) {
    __shared__ float sh_inv[4][8];
    int wid = threadIdx.x >> 6, lane = threadIdx.x & 63;
    int n = blockIdx.x * 4 + wid;
    int rpv = (lane <= 8) ? rp[n * RR + lane] : 0;
    int nxt = __shfl(rpv, (lane + 1) & 63);
    if (lane < 8) sh_inv[wid][lane] = 1.f / (float)((nxt - rpv) > 0 ? (nxt - rpv) : 1);
    int q = lane & 7;
    int beg = rp[n * RR], end = rp[n * RR + RR];
    float4 acc = make_float4(0.f, 0.f, 0.f, 0.f);
    int k = beg + (lane >> 3);
    for (; k + 8 < end; k += 16) {
        int key0 = srcs2[k], key1 = srcs2[k + 8];
        int s0 = key0 >> 3, s1 = key1 >> 3;
        int g0 = key0 & 7, g1 = key1 & 7;
        float e0 = sh_inv[wid][g0], e1 = sh_inv[wid][g1];
        float4 v0 = h4tof4(*(const h4*)(y + ((size_t)(g0 >> 1) * NN + s0) * 64 + (g0 & 1) * 32 + q * 4));
        float4 v1 = h4tof4(*(const h4*)(y + ((size_t)(g1 >> 1) * NN + s1) * 64 + (g1 & 1) * 32 + q * 4));
        fmacc(acc, v0, e0);
        fmacc(acc, v1, e1);
    }
    if (k < end) {
        int key0 = srcs2[k];
        int s0 = key0 >> 3;
        int g0 = key0 & 7;
        float4 v0 = h4tof4(*(const h4*)(y + ((size_t)(g0 >> 1) * NN + s0) * 64 + (g0 & 1) * 32 + q * 4));
        fmacc(acc, v0, sh_inv[wid][g0]);
    }
    red4(acc, 8);
    red4(acc, 16);
    red4(acc, 32);
    if (lane < 8) {
        float4 prev = *(const float4*)(x3prev + (size_t)n * 64 + q * 4);
        float4 b = *(const float4*)(bias + q * 4);
        float4 v;
        v.x = fmaxf(prev.x + acc.x + b.x, 0.f);
        v.y = fmaxf(prev.y + acc.y + b.y, 0.f);
        v.z = fmaxf(prev.z + acc.z + b.z, 0.f);
        v.w = fmaxf(prev.w + acc.w + b.w, 0.f);
        h4 hv = {(f16)v.x, (f16)v.y, (f16)v.z, (f16)v.w};
        *(h4*)(x3h + (size_t)n * 32 + q * 4) = hv;
        // fused alds2: al[j] = sum_c x3[n][c] * U2p[c*64+j], c = q*4..q*4+3 per lane
        float al[8];
#pragma unroll
        for (int j = 0; j < 8; j++) {
            al[j] = fmaf(v.x, U2p[(q * 4 + 0) * 64 + j],
                    fmaf(v.y, U2p[(q * 4 + 1) * 64 + j],
                    fmaf(v.z, U2p[(q * 4 + 2) * 64 + j],
                         v.w * U2p[(q * 4 + 3) * 64 + j])));
        }
#pragma unroll
        for (int m = 1; m < 8; m <<= 1) {
#pragma unroll
            for (int j = 0; j < 8; j++) al[j] += __shfl_xor(al[j], m);
        }
        alds[n * 8 + q] = al[q];
    }
}

// ===== fused GAT aggregation; X gathered as fp16 (LDX in f16 elements) =====
template <int F, int LDX = F>
__global__ __launch_bounds__(256) void k_gatx(const int* __restrict__ rp,
                                              const int* __restrict__ srcs2,
                                              const float* __restrict__ alds,
                                              const f16* __restrict__ X,
                                              float* __restrict__ msg) {
    constexpr int G = F / 4;    // lanes per edge-group (16 or 8)
    constexpr int NG = 64 / G;  // groups per wave (4 or 8)
    int wid = threadIdx.x >> 6, lane = threadIdx.x & 63;
    int n = blockIdx.x * 4 + wid;
    if (n >= NN) return;
    int g = lane / G, q = lane % G;
    float4 ald4 = *(const float4*)(alds + n * 8 + 4);
    float4 acc0 = make_float4(0.f, 0.f, 0.f, 0.f);
    float4 acc1 = acc0, acc2 = acc0, acc3 = acc0;
    float4 z = make_float4(0.f, 0.f, 0.f, 0.f);
    if (g == 0) {  // self loop
        float4 a4 = *(const float4*)(alds + n * 8);
        float4 xv = h4tof4(*(const h4*)(X + (size_t)n * LDX + q * 4));
        float p0 = __expf(leaky(a4.x + ald4.x));
        float p1 = __expf(leaky(a4.y + ald4.y));
        float p2 = __expf(leaky(a4.z + ald4.z));
        float p3 = __expf(leaky(a4.w + ald4.w));
        z = make_float4(p0, p1, p2, p3);
        fmacc(acc0, xv, p0);
        fmacc(acc1, xv, p1);
        fmacc(acc2, xv, p2);
        fmacc(acc3, xv, p3);
    }
    int beg = rp[n * RR], end = rp[n * RR + RR];
    int k = beg + g;
    for (; k + NG < end; k += 2 * NG) {
        int s0 = srcs2[k] >> 3, s1 = srcs2[k + NG] >> 3;
        float4 a0 = *(const float4*)(alds + s0 * 8);
        float4 a1 = *(const float4*)(alds + s1 * 8);
        float4 x0 = h4tof4(*(const h4*)(X + (size_t)s0 * LDX + q * 4));
        float4 x1v = h4tof4(*(const h4*)(X + (size_t)s1 * LDX + q * 4));
        float p00 = __expf(leaky(a0.x + ald4.x)), p01 = __expf(leaky(a0.y + ald4.y));
        float p02 = __expf(leaky(a0.z + ald4.z)), p03 = __expf(leaky(a0.w + ald4.w));
        float p10 = __expf(leaky(a1.x + ald4.x)), p11 = __expf(leaky(a1.y + ald4.y));
        float p12 = __expf(leaky(a1.z + ald4.z)), p13 = __expf(leaky(a1.w + ald4.w));
        z.x += p00 + p10;
        z.y += p01 + p11;
        z.z += p02 + p12;
        z.w += p03 + p13;
        fmacc(acc0, x0, p00);
        fmacc(acc1, x0, p01);
        fmacc(acc2, x0, p02);
        fmacc(acc3, x0, p03);
        fmacc(acc0, x1v, p10);
        fmacc(acc1, x1v, p11);
        fmacc(acc2, x1v, p12);
        fmacc(acc3, x1v, p13);
    }
    if (k < end) {
        int s0 = srcs2[k] >> 3;
        float4 a0 = *(const float4*)(alds + s0 * 8);
        float4 x0 = h4tof4(*(const h4*)(X + (size_t)s0 * LDX + q * 4));
        float p00 = __expf(leaky(a0.x + ald4.x)), p01 = __expf(leaky(a0.y + ald4.y));
        float p02 = __expf(leaky(a0.z + ald4.z)), p03 = __expf(leaky(a0.w + ald4.w));
        z.x += p00;
        z.y += p01;
        z.z += p02;
        z.w += p03;
        fmacc(acc0, x0, p00);
        fmacc(acc1, x0, p01);
        fmacc(acc2, x0, p02);
        fmacc(acc3, x0, p03);
    }
#pragma unroll
    for (int m = G; m < 64; m <<= 1) {
        red4(acc0, m);
        red4(acc1, m);
        red4(acc2, m);
        red4(acc3, m);
        red4(z, m);
    }
    if (g == 0) {
        float4 iz = make_float4(1.f / z.x, 1.f / z.y, 1.f / z.z, 1.f / z.w);
        float* mp = msg + (size_t)n * 4 * F + q * 4;
        *(float4*)(mp + 0 * F) = make_float4(acc0.x * iz.x, acc0.y * iz.x, acc0.z * iz.x, acc0.w * iz.x);
        *(float4*)(mp + 1 * F) = make_float4(acc1.x * iz.y, acc1.y * iz.y, acc1.z * iz.y, acc1.w * iz.y);
        *(float4*)(mp + 2 * F) = make_float4(acc2.x * iz.z, acc2.y * iz.z, acc2.z * iz.z, acc2.w * iz.z);
        *(float4*)(mp + 3 * F) = make_float4(acc3.x * iz.w, acc3.y * iz.w, acc3.z * iz.w, acc3.w * iz.w);
    }
}

extern "C" void kernel_launch(void* const* d_in, const int* in_sizes, int n_in,
                              void* d_out, int out_size, void* d_ws, size_t ws_size,
                              hipStream_t stream) {
    const float* x      = (const float*)d_in[0];
    const int*   ei     = (const int*)d_in[1];
    const int*   et     = (const int*)d_in[2];
    const float* basis1 = (const float*)d_in[3];
    const float* comp1  = (const float*)d_in[4];
    const float* root1  = (const float*)d_in[5];
    const float* brg1   = (const float*)d_in[6];
    const float* wg1    = (const float*)d_in[7];
    const float* asrc1  = (const float*)d_in[8];
    const float* adst1  = (const float*)d_in[9];
    const float* bg1    = (const float*)d_in[10];
    const float* basis2 = (const float*)d_in[11];
    const float* comp2  = (const float*)d_in[12];
    const float* root2  = (const float*)d_in[13];
    const float* brg2   = (const float*)d_in[14];
    const float* wg2    = (const float*)d_in[15];
    const float* asrc2  = (const float*)d_in[16];
    const float* adst2  = (const float*)d_in[17];
    const float* bg2    = (const float*)d_in[18];
    const int* src = ei;
    const int* dst = ei + EE;
    float* out = (float*)d_out;

    // ---- int region ----
    int* wsi = (int*)d_ws;
    size_t ioff = 0;
    auto ialloc = [&](size_t n) { int* p = wsi + ioff; ioff += (n + 3) & ~(size_t)3; return p; };
    int* cnt2 = ialloc(SEGS);  // reused as fill cursors (wo)
    int* rp   = ialloc(SEGS + 1);
    int* bsum = ialloc(2048);
    int* srcs2 = ialloc(EE);
    int* wo = cnt2;
    // ---- float region ----
    float* wsf = (float*)(wsi + ioff);
    size_t total_f = (ws_size - ioff * sizeof(int)) / sizeof(float);
    size_t P_f = (size_t)NN * 320;
    size_t need_f = P_f + (size_t)NN * 128
                  + 40960 + 20480 + 16384 + 8192 + 4096 + 2048
                  + (size_t)NN * 8
                  + 20480 + 8192 + 40960
                  + (size_t)NN * 32 + (size_t)NN * 16 + 64;  // x1h, x3h (fp16)
    if (total_f < need_f) return;  // loud fail: output stays zero
    size_t foff = 0;
    auto falloc = [&](size_t n) { float* p = wsf + foff; foff += (n + 3) & ~(size_t)3; return p; };
    float* P      = falloc(P_f);
    float* x2     = falloc((size_t)NN * 128);
    float* Wcat2e = falloc(40960);           // [128][320]: root2(pad) | W_r pairs
    float* Wb1    = falloc(20480);           // [320][64]: basis1 rows | root1 rows
    float* wg1r   = falloc(16384);
    float* Wstk   = falloc(8192);
    float* U1p    = falloc(4096);
    float* U2p    = falloc(2048);
    float* alds   = falloc((size_t)NN * 8);
    short* Wb1pk  = (short*)falloc(20480);   // 40 pairs x 1024 shorts
    short* wg1rpk = (short*)falloc(8192);    // 16 pairs
    short* Wcatpk = (short*)falloc(40960);   // 80 pairs (5 panels x 16)
    f16* x1h      = (f16*)falloc((size_t)NN * 32);  // [n][64] fp16
    f16* x3h      = (f16*)falloc((size_t)NN * 16);  // [n][32] fp16
    float* Ubuf = P;                  // L1 basis-gather output [n][320]
    float* x1   = x2 + (size_t)NN * 64;  // dead before msg1-gemm overwrites x2 region
    float* msg1 = P;                  // [n][4][64] (U dead after u-gemm)
    float* x3   = P;                  // fp32 root-panel out (read as prev by agg2)
    f16* ybuf3h = (f16*)(P + (size_t)NN * 64);  // L3 rel panels [4][n][64] fp16
    float* msg2 = P + (size_t)NN * 64;   // [n][4][32] (ybuf3h dead after agg2)

    const int EB = (EE + 255) / 256;
    const int NB4 = (NN + 3) / 4;    // NN % 4 == 0 -> exact
    const int NB32 = (NN + 31) / 32; // 1563 (skinny matvec blocks, 32 nodes each)

    // ---- CSR build ----
    hipMemsetAsync(cnt2, 0, SEGS * sizeof(int), stream);
    k_count2<<<EB, 256, 0, stream>>>(dst, et, cnt2);
    k_scanA<<<NBLK, 256, 0, stream>>>(cnt2, rp, bsum);
    k_scanB<<<1, 256, 0, stream>>>(bsum);
    k_scanC<<<NBLK, 256, 0, stream>>>(rp, bsum, wo);
    k_fill<<<EB, 256, 0, stream>>>(src, dst, et, wo, srcs2);
    k_prep<<<(92160 + 255) / 256, 256, 0, stream>>>(
        wg1, wg2, root1, root2, basis1, basis2, comp2, asrc1, adst1, asrc2, adst2,
        Wcat2e, wg1r, Wstk, U1p, U2p, Wb1);
    k_pack<<<34, 256, 0, stream>>>(Wb1, wg1r, Wcat2e, Wb1pk, wg1rpk, Wcatpk);

    // ---- layer 1: RGCN(64->64)+relu via basis-space gather + one K=320 MFMA GEMM ----
    k_gagg1<<<NB4, 256, 0, stream>>>(rp, srcs2, comp1, x, Ubuf);
    k_mfma<320, 64, 2><<<dim3(NTW, 1), 256, 0, stream>>>(Ubuf, 320, 0, Wb1pk, 0,
                                                         x1, 64, 0, brg1, 0);

    // ---- layer 2: GAT(64 -> 4x32 concat), fp16 gather of x1 ----
    k_alds1<<<NB32, 256, 0, stream>>>(x1, U1p, alds, x1h);
    k_gatx<64, 64><<<NB4, 256, 0, stream>>>(rp, srcs2, alds, x1h, msg1);
    k_mfma<64, 32, 0><<<dim3(NTW, 4), 256, 0, stream>>>(msg1, 256, 64, wg1rpk, 4096,
                                                        x2, 128, 32, bg1, 32);

    // ---- layer 3: RGCN(128->32)+relu; root fp32 + 4 rel panels fp16 via MFMA ----
    k_mfma<128, 64, 0, 0><<<dim3(NTW, 1), 256, 0, stream>>>(x2, 128, 0, Wcatpk, 0,
                                                            P, 64, 0, nullptr, 0);
    k_mfma<128, 64, 0, 1><<<dim3(NTW, 4), 256, 0, stream>>>(x2, 128, 0, Wcatpk + 16384, 16384,
                                                            (float*)ybuf3h, 64, (size_t)NN * 64,
                                                            nullptr, 0);
    k_agg2<<<NB4, 256, 0, stream>>>(rp, srcs2, ybuf3h, brg2, U2p, x3, x3h, alds);

    // ---- layer 4: GAT(32 -> 4x16, mean heads) + relu + tanh, fp16 gather of x3 ----
    k_gatx<32, 32><<<NB4, 256, 0, stream>>>(rp, srcs2, alds, x3h, msg2);
    k_final<<<NB32, 256, 0, stream>>>(msg2, Wstk, bg2, out);
}

// Round 6
// 441.240 us; speedup vs baseline: 1.2295x; 1.0412x over previous
//
#include <hip/hip_runtime.h>
#include <math.h>

#define NN 50000
#define EE 800000
#define RR 8
#define SLOPE 0.2f
#define SEGS (NN * RR)            /* 400000 per-(node,relation) segments */
#define NBLK ((SEGS + 255) / 256) /* 1563 scan blocks */
#define NTW ((NN + 63) / 64)      /* 782 mfma row-tiles (64 rows each) */
#define NBUK 98                   /* coarse buckets: dst>>9 (512 dst values each) */
#define SEGB 4096                 /* segments per bucket = 512 * RR */
#define EB4 ((EE + 4095) / 4096)  /* 196 fillA blocks */

typedef __attribute__((ext_vector_type(8))) short bf16x8;
typedef __attribute__((ext_vector_type(4))) float f32x4;
typedef _Float16 f16;
typedef __attribute__((ext_vector_type(4))) _Float16 h4;
typedef __attribute__((ext_vector_type(8))) _Float16 h8;

__device__ __forceinline__ float leaky(float v) { return v >= 0.f ? v : SLOPE * v; }

__device__ __forceinline__ void fmacc(float4& a, const float4& v, float p) {
    a.x = fmaf(v.x, p, a.x);
    a.y = fmaf(v.y, p, a.y);
    a.z = fmaf(v.z, p, a.z);
    a.w = fmaf(v.w, p, a.w);
}

__device__ __forceinline__ void red4(float4& a, int m) {
    a.x += __shfl_xor(a.x, m);
    a.y += __shfl_xor(a.y, m);
    a.z += __shfl_xor(a.z, m);
    a.w += __shfl_xor(a.w, m);
}

__device__ __forceinline__ float4 h4tof4(h4 t) {
    return make_float4((float)t.x, (float)t.y, (float)t.z, (float)t.w);
}

// split 8 fp32 -> bf16 hi (truncate) + bf16 lo (truncate of exact residual).
__device__ __forceinline__ void split8(const float4& v0, const float4& v1,
                                       bf16x8& hi, bf16x8& lo) {
    float e[8] = {v0.x, v0.y, v0.z, v0.w, v1.x, v1.y, v1.z, v1.w};
    union { bf16x8 v; unsigned u[4]; } H, L;
#pragma unroll
    for (int j = 0; j < 4; j++) {
        unsigned b0 = __float_as_uint(e[2 * j]), b1 = __float_as_uint(e[2 * j + 1]);
        unsigned h0 = b0 & 0xFFFF0000u, h1 = b1 & 0xFFFF0000u;
        H.u[j] = (h0 >> 16) | h1;
        float l0 = e[2 * j] - __uint_as_float(h0);
        float l1 = e[2 * j + 1] - __uint_as_float(h1);
        L.u[j] = (__float_as_uint(l0) >> 16) | (__float_as_uint(l1) & 0xFFFF0000u);
    }
    hi = H.v;
    lo = L.v;
}

// ============================ CSR build ============================
__global__ void k_count2(const int* __restrict__ dst, const int* __restrict__ et,
                         int* __restrict__ cnt2) {
    int e = blockIdx.x * 256 + threadIdx.x;
    if (e < EE) atomicAdd(&cnt2[dst[e] * RR + et[e]], 1);
}

__global__ void k_scanA(const int* __restrict__ cnt2, int* __restrict__ rp,
                        int* __restrict__ bsum) {
    __shared__ int sh[256];
    int t = threadIdx.x;
    int i = blockIdx.x * 256 + t;
    int v = (i < SEGS) ? cnt2[i] : 0;
    sh[t] = v;
    __syncthreads();
    for (int off = 1; off < 256; off <<= 1) {
        int u = (t >= off) ? sh[t - off] : 0;
        __syncthreads();
        sh[t] += u;
        __syncthreads();
    }
    if (i < SEGS) rp[i] = sh[t] - v;
    if (t == 255) bsum[blockIdx.x] = sh[255];
}

__global__ void k_scanB(int* __restrict__ bsum) {
    __shared__ int sh[256];
    int t = threadIdx.x;
    int loc[8];
    int s = 0;
#pragma unroll
    for (int i = 0; i < 8; i++) {
        int idx = t * 8 + i;
        int v = (idx < NBLK) ? bsum[idx] : 0;
        loc[i] = v;
        s += v;
    }
    sh[t] = s;
    __syncthreads();
    for (int off = 1; off < 256; off <<= 1) {
        int u = (t >= off) ? sh[t - off] : 0;
        __syncthreads();
        sh[t] += u;
        __syncthreads();
    }
    int run = sh[t] - s;
#pragma unroll
    for (int i = 0; i < 8; i++) {
        int idx = t * 8 + i;
        if (idx < NBLK) {
            int v = loc[i];
            bsum[idx] = run;
            run += v;
        }
    }
}

__global__ void k_scanC(int* __restrict__ rp, const int* __restrict__ bsum) {
    int i = blockIdx.x * 256 + threadIdx.x;
    if (i < SEGS) rp[i] += bsum[blockIdx.x];
    if (i == 0) rp[SEGS] = EE;
}

__global__ void k_initcb(const int* __restrict__ rp, int* __restrict__ cbcur) {
    int t = threadIdx.x;
    if (t < NBUK) cbcur[t] = rp[t * SEGB];
}

// ===== fill phase A: bin edges into recbuf in coarse-bucket-major order =====
// rec = (dst&511)<<19 | src<<3 | rel (28 bits). Per-block run reservation makes the
// writes dense 168-B runs -> L2 line fill instead of 16x partial-line amplification.
__global__ __launch_bounds__(256) void k_fillA(const int* __restrict__ src,
                                               const int* __restrict__ dst,
                                               const int* __restrict__ et,
                                               int* __restrict__ cbcur,
                                               int* __restrict__ recbuf) {
    __shared__ int hist[NBUK], lcur[NBUK], gres[NBUK];
    int tid = threadIdx.x;
    int e0 = blockIdx.x * 4096;
    int cnt = EE - e0;
    if (cnt > 4096) cnt = 4096;
    for (int i = tid; i < NBUK; i += 256) { hist[i] = 0; lcur[i] = 0; }
    __syncthreads();
    int myb[16], myrec[16];
#pragma unroll
    for (int j = 0; j < 16; j++) {
        int i = tid + j * 256;
        if (i < cnt) {
            int e = e0 + i;
            int d = dst[e];
            int b = d >> 9;
            myb[j] = b;
            myrec[j] = ((d & 511) << 19) | (src[e] << 3) | et[e];
            atomicAdd(&hist[b], 1);
        } else {
            myb[j] = -1;
            myrec[j] = 0;
        }
    }
    __syncthreads();
    if (tid < NBUK) gres[tid] = atomicAdd(&cbcur[tid], hist[tid]);
    __syncthreads();
#pragma unroll
    for (int j = 0; j < 16; j++) {
        if (myb[j] >= 0) {
            int p = atomicAdd(&lcur[myb[j]], 1);
            recbuf[gres[myb[j]] + p] = myrec[j];
        }
    }
}

// ===== fill phase B: one block per bucket; LDS segment cursors; block-exclusive =====
// 32 KB scatter window stays in this block's XCD L2 -> dense writeback (no bouncing).
__global__ __launch_bounds__(256) void k_fillB(const int* __restrict__ rp,
                                               const int* __restrict__ recbuf,
                                               int* __restrict__ srcs2) {
    __shared__ int cur[SEGB];
    int b = blockIdx.x;
    int segbase = b * SEGB;
    int nseg = SEGS - segbase;
    if (nseg > SEGB) nseg = SEGB;
    int base = rp[segbase];
    int tid = threadIdx.x;
    for (int s = tid; s < SEGB; s += 256)
        cur[s] = (s < nseg) ? (rp[segbase + s] - base) : 0;
    __syncthreads();
    int limit = rp[segbase + nseg];  // nseg==SEGB normally; last bucket -> rp[SEGS]=EE
    int cnt = limit - base;
    for (int i = tid; i < cnt; i += 256) {
        int rec = recbuf[base + i];
        int segl = ((rec >> 19) << 3) | (rec & 7);
        int p = atomicAdd(&cur[segl], 1);
        srcs2[base + p] = rec & 0x7FFFF;
    }
}

// ==== prep (merged): padded weights, logit projections, stacked Wb1, Wcat2e compose ====
__global__ void k_prep(const float* __restrict__ wg1, const float* __restrict__ wg2,
                       const float* __restrict__ root1, const float* __restrict__ root2,
                       const float* __restrict__ basis1, const float* __restrict__ basis2,
                       const float* __restrict__ comp2,
                       const float* __restrict__ asrc1, const float* __restrict__ adst1,
                       const float* __restrict__ asrc2, const float* __restrict__ adst2,
                       float* __restrict__ Wcat2e, float* __restrict__ wg1r,
                       float* __restrict__ Wstk, float* __restrict__ U1p,
                       float* __restrict__ U2p, float* __restrict__ Wb1) {
    int idx = blockIdx.x * 256 + threadIdx.x;
    if (idx < 16384) {  // wg1r[h][k][c] (c<32 valid)
        int h = idx >> 12, kc = idx & 4095;
        int k = kc >> 6, c = kc & 63;
        wg1r[idx] = (c < 32) ? wg1[k * 128 + h * 32 + c] : 0.f;
    } else if (idx < 24576) {  // Wstk[h*32+k][c] = wg2[k][h*16+c] (c<16 valid)
        int j = idx - 16384;
        int row = j >> 6, c = j & 63;
        int h = row >> 5, k = row & 31;
        Wstk[j] = (c < 16) ? wg2[k * 64 + h * 16 + c] : 0.f;
    } else if (idx < 32768) {  // Wcat2e root block: [128][col 0-63] = root2 zero-padded
        int j = idx - 24576;
        int k = j >> 6, c = j & 63;
        Wcat2e[k * 320 + c] = (c < 32) ? root2[k * 32 + c] : 0.f;
    } else if (idx < 36864) {  // U1p[k][j]: j<4 src head j, 4<=j<8 dst head j-4, else 0
        int j0 = idx - 32768;
        int k = j0 >> 6, j = j0 & 63;
        float s = 0.f;
        if (j < 8) {
            int h = j & 3;
            const float* a = (j < 4) ? asrc1 : adst1;
            for (int c = 0; c < 32; c++) s += wg1[k * 128 + h * 32 + c] * a[h * 32 + c];
        }
        U1p[j0] = s;
    } else if (idx < 38912) {  // U2p[k][j]
        int j0 = idx - 36864;
        int k = j0 >> 6, j = j0 & 63;
        float s = 0.f;
        if (j < 8) {
            int h = j & 3;
            const float* a = (j < 4) ? asrc2 : adst2;
            for (int c = 0; c < 16; c++) s += wg2[k * 64 + h * 16 + c] * a[h * 16 + c];
        }
        U2p[j0] = s;
    } else if (idx < 55296) {  // Wb1 rows 0-255 = basis1 [4][64][64] flat copy
        Wb1[idx - 38912] = basis1[idx - 38912];
    } else if (idx < 59392) {  // Wb1 rows 256-319 = root1
        Wb1[idx - 38912] = root1[idx - 55296];
    } else if (idx < 92160) {  // Wcat2e basis-composed block: [128][col 64-319]
        int j = idx - 59392;
        int i = j >> 8, rc = j & 255;
        int r = rc >> 5, o = rc & 31;
        float acc = 0.f;
#pragma unroll
        for (int b = 0; b < 4; b++) acc += comp2[r * 4 + b] * basis2[b * 4096 + i * 32 + o];
        Wcat2e[i * 320 + 64 + rc] = acc;
    }
}

// ==== pack weights into bf16 hi/lo MFMA fragment order ====
__global__ void k_pack(const float* __restrict__ Wb1, const float* __restrict__ wg1r,
                       const float* __restrict__ Wcat, short* __restrict__ pWb1,
                       short* __restrict__ pwg1r, short* __restrict__ pWcat) {
    int u = blockIdx.x * 256 + threadIdx.x;
    int lane = u & 63, pair = u >> 6;
    if (pair >= 136) return;
    int m = lane & 15, g = lane >> 4;
    const float* src;
    int ldB, col, k0;
    short* dst;
    if (pair < 40) {
        int ct = pair / 10, kc = pair % 10;
        src = Wb1; ldB = 64; col = ct * 16 + m; k0 = kc * 32 + g * 8;
        dst = pWb1 + pair * 1024 + lane * 8;
    } else if (pair < 56) {
        int q = pair - 40;
        int h = q >> 2, lp = q & 3, ct = lp >> 1, kc = lp & 1;
        src = wg1r + h * 4096; ldB = 64; col = ct * 16 + m; k0 = kc * 32 + g * 8;
        dst = pwg1r + q * 1024 + lane * 8;
    } else {
        int q = pair - 56;
        int p = q >> 4, lp = q & 15, ct = lp >> 2, kc = lp & 3;
        src = Wcat; ldB = 320; col = p * 64 + ct * 16 + m; k0 = kc * 32 + g * 8;
        dst = pWcat + q * 1024 + lane * 8;
    }
    float e[8];
#pragma unroll
    for (int r = 0; r < 8; r++) e[r] = src[(size_t)(k0 + r) * ldB + col];
    union { bf16x8 v; unsigned u4[4]; } H, L;
#pragma unroll
    for (int j = 0; j < 4; j++) {
        unsigned b0 = __float_as_uint(e[2 * j]), b1 = __float_as_uint(e[2 * j + 1]);
        unsigned h0 = b0 & 0xFFFF0000u, h1 = b1 & 0xFFFF0000u;
        H.u4[j] = (h0 >> 16) | h1;
        float l0 = e[2 * j] - __uint_as_float(h0);
        float l1 = e[2 * j + 1] - __uint_as_float(h1);
        L.u4[j] = (__float_as_uint(l0) >> 16) | (__float_as_uint(l1) & 0xFFFF0000u);
    }
    *(bf16x8*)dst = H.v;
    *(bf16x8*)(dst + 512) = L.v;
}

// ============ MFMA GEMM: block = 4 waves x 16 rows = 64 rows, NCOL cols ============
template <int KTOT, int NCOL, int ACT = 0, int OUTH = 0>
__global__ __launch_bounds__(256) void k_mfma(const float* __restrict__ X, int ldX, int xmb,
                                              const short* __restrict__ Bpk, int bmb,
                                              float* __restrict__ Y, int ldY, size_t ymb,
                                              const float* __restrict__ bias, int biasmb) {
    constexpr int NKC = KTOT / 32;
    constexpr int NCT = NCOL / 16;
    const int tid = threadIdx.x;
    const int wid = tid >> 6, lane = tid & 63;
    const int m = lane & 15, g = lane >> 4;
    const int mb = blockIdx.y;
    const int rowbase = blockIdx.x * 64 + wid * 16;
    if (rowbase >= NN) return;  // NN % 16 == 0: per-wave all-or-nothing
    const float* Xm = X + (size_t)mb * xmb + (size_t)(rowbase + m) * ldX;
    const short* Bm = Bpk + (size_t)mb * bmb;

    f32x4 acc[NCT];
#pragma unroll
    for (int c = 0; c < NCT; c++) acc[c] = (f32x4){0.f, 0.f, 0.f, 0.f};

#pragma unroll
    for (int kc = 0; kc < NKC; kc++) {
        float4 v0 = *(const float4*)(Xm + kc * 32 + g * 8);
        float4 v1 = *(const float4*)(Xm + kc * 32 + g * 8 + 4);
        bf16x8 ah, al;
        split8(v0, v1, ah, al);
#pragma unroll
        for (int ct = 0; ct < NCT; ct++) {
            const short* bp = Bm + (size_t)(ct * NKC + kc) * 1024 + lane * 8;
            bf16x8 bh = *(const bf16x8*)bp;
            bf16x8 bl = *(const bf16x8*)(bp + 512);
            acc[ct] = __builtin_amdgcn_mfma_f32_16x16x32_bf16(ah, bh, acc[ct], 0, 0, 0);
            acc[ct] = __builtin_amdgcn_mfma_f32_16x16x32_bf16(al, bh, acc[ct], 0, 0, 0);
            acc[ct] = __builtin_amdgcn_mfma_f32_16x16x32_bf16(ah, bl, acc[ct], 0, 0, 0);
        }
    }

#pragma unroll
    for (int ct = 0; ct < NCT; ct++) {
        int col = ct * 16 + m;
        float bv = bias ? bias[mb * biasmb + col] : 0.f;
#pragma unroll
        for (int i = 0; i < 4; i++) {
            float o = acc[ct][i] + bv;
            if (ACT == 2) o = fmaxf(o, 0.f);
            if (OUTH) {
                f16* Yh = (f16*)Y;
                Yh[(size_t)mb * ymb + (size_t)(rowbase + g * 4 + i) * ldY + col] = (f16)o;
            } else {
                Y[(size_t)mb * ymb + (size_t)(rowbase + g * 4 + i) * ldY + col] = o;
            }
        }
    }
}

// ===== L1 basis-space gather: U[n][b][64] = sum_edges comp[r,b]*inv_cnt*x[src]; U[n][4][64]=x[n] =====
__global__ __launch_bounds__(256) void k_gagg1(const int* __restrict__ rp,
                                               const int* __restrict__ srcs2,
                                               const float* __restrict__ comp,
                                               const float* __restrict__ X,
                                               float* __restrict__ U) {
    __shared__ float4 sh_w[4][8];
    int wid = threadIdx.x >> 6, lane = threadIdx.x & 63;
    int n = blockIdx.x * 4 + wid;
    int rpv = (lane <= 8) ? rp[n * RR + lane] : 0;
    int nxt = __shfl(rpv, (lane + 1) & 63);
    if (lane < 8) {
        float inv = 1.f / (float)((nxt - rpv) > 0 ? (nxt - rpv) : 1);
        float4 c = *(const float4*)(comp + lane * 4);
        sh_w[wid][lane] = make_float4(c.x * inv, c.y * inv, c.z * inv, c.w * inv);
    }
    int q = lane & 15;
    int beg = rp[n * RR], end = rp[n * RR + RR];
    float4 a0 = make_float4(0.f, 0.f, 0.f, 0.f);
    float4 a1 = a0, a2 = a0, a3 = a0;
    int k = beg + (lane >> 4);
    for (; k + 4 < end; k += 8) {
        int key0 = srcs2[k], key1 = srcs2[k + 4];
        float4 w0 = sh_w[wid][key0 & 7], w1 = sh_w[wid][key1 & 7];
        float4 v0 = *(const float4*)(X + (size_t)(key0 >> 3) * 64 + q * 4);
        float4 v1 = *(const float4*)(X + (size_t)(key1 >> 3) * 64 + q * 4);
        fmacc(a0, v0, w0.x);
        fmacc(a1, v0, w0.y);
        fmacc(a2, v0, w0.z);
        fmacc(a3, v0, w0.w);
        fmacc(a0, v1, w1.x);
        fmacc(a1, v1, w1.y);
        fmacc(a2, v1, w1.z);
        fmacc(a3, v1, w1.w);
    }
    if (k < end) {
        int key0 = srcs2[k];
        float4 w0 = sh_w[wid][key0 & 7];
        float4 v0 = *(const float4*)(X + (size_t)(key0 >> 3) * 64 + q * 4);
        fmacc(a0, v0, w0.x);
        fmacc(a1, v0, w0.y);
        fmacc(a2, v0, w0.z);
        fmacc(a3, v0, w0.w);
    }
    red4(a0, 16); red4(a0, 32);
    red4(a1, 16); red4(a1, 32);
    red4(a2, 16); red4(a2, 32);
    red4(a3, 16); red4(a3, 32);
    if (lane < 16) {
        float* un = U + (size_t)n * 320;
        *(float4*)(un + 0 * 64 + q * 4) = a0;
        *(float4*)(un + 1 * 64 + q * 4) = a1;
        *(float4*)(un + 2 * 64 + q * 4) = a2;
        *(float4*)(un + 3 * 64 + q * 4) = a3;
        *(float4*)(un + 256 + q * 4) = *(const float4*)(X + (size_t)n * 64 + q * 4);
    }
}

// ===== skinny matvec + x1h emit: alds[n][j] = sum_c x1[n][c]*U1p[c*64+j]; x1h = fp16(x1) =====
__global__ __launch_bounds__(256) void k_alds1(const float* __restrict__ X,
                                               const float* __restrict__ U1p,
                                               float* __restrict__ alds,
                                               f16* __restrict__ x1h) {
    __shared__ float sUT[8 * 68];  // sUT[j][c] = U1p[c*64 + j]
    int tid = threadIdx.x;
    for (int i = tid; i < 512; i += 256) {
        int j = i >> 6, c = i & 63;
        sUT[j * 68 + c] = U1p[c * 64 + j];
    }
    __syncthreads();
    int lane = tid & 63, wid = tid >> 6;
    int n = blockIdx.x * 32 + wid * 8 + (lane >> 3);
    int q = lane & 7;  // owns c-slice q*8..q*8+7
    float x[8];
    if (n < NN) {
        float4 v0 = *(const float4*)(X + (size_t)n * 64 + q * 8);
        float4 v1 = *(const float4*)(X + (size_t)n * 64 + q * 8 + 4);
        x[0] = v0.x; x[1] = v0.y; x[2] = v0.z; x[3] = v0.w;
        x[4] = v1.x; x[5] = v1.y; x[6] = v1.z; x[7] = v1.w;
        h8 hv;
#pragma unroll
        for (int c = 0; c < 8; c++) hv[c] = (f16)x[c];
        *(h8*)(x1h + (size_t)n * 64 + q * 8) = hv;
    } else {
#pragma unroll
        for (int c = 0; c < 8; c++) x[c] = 0.f;
    }
    float al[8];
#pragma unroll
    for (int j = 0; j < 8; j++) {
        const float* u = &sUT[j * 68 + q * 8];
        float s = 0.f;
#pragma unroll
        for (int c = 0; c < 8; c++) s += x[c] * u[c];
        al[j] = s;
    }
#pragma unroll
    for (int m = 1; m < 8; m <<= 1)
#pragma unroll
        for (int j = 0; j < 8; j++) al[j] += __shfl_xor(al[j], m);
    if (n < NN) alds[(size_t)n * 8 + q] = al[q];
}

// ===== skinny final: out[n][c<16] = tanh(relu(0.25*sum_k msg2[n][k]*Wstk[k][c] + bg2[c])) =====
__global__ __launch_bounds__(256) void k_final(const float* __restrict__ Xm,
                                               const float* __restrict__ Wstk,
                                               const float* __restrict__ bg2,
                                               float* __restrict__ out) {
    __shared__ float sWT[16 * 132];  // sWT[c][k] = Wstk[k*64 + c]
    int tid = threadIdx.x;
    for (int i = tid; i < 2048; i += 256) {
        int c = i >> 7, k = i & 127;
        sWT[c * 132 + k] = Wstk[k * 64 + c];
    }
    __syncthreads();
    int lane = tid & 63, wid = tid >> 6;
    int n = blockIdx.x * 32 + wid * 8 + (lane >> 3);
    int q = lane & 7;  // owns k in {t*32 + q*4 + s}: conflict-free q*4 stride in LDS
    float x[16];
    if (n < NN) {
#pragma unroll
        for (int t = 0; t < 4; t++) {
            float4 v = *(const float4*)(Xm + (size_t)n * 128 + t * 32 + q * 4);
            x[t * 4 + 0] = v.x; x[t * 4 + 1] = v.y; x[t * 4 + 2] = v.z; x[t * 4 + 3] = v.w;
        }
    } else {
#pragma unroll
        for (int k = 0; k < 16; k++) x[k] = 0.f;
    }
    float al[16];
#pragma unroll
    for (int c = 0; c < 16; c++) {
        float s = 0.f;
#pragma unroll
        for (int t = 0; t < 4; t++) {
            const float* w = &sWT[c * 132 + t * 32 + q * 4];
            s += x[t * 4 + 0] * w[0] + x[t * 4 + 1] * w[1] + x[t * 4 + 2] * w[2] +
                 x[t * 4 + 3] * w[3];
        }
        al[c] = s;
    }
#pragma unroll
    for (int m = 1; m < 8; m <<= 1)
#pragma unroll
        for (int c = 0; c < 16; c++) al[c] += __shfl_xor(al[c], m);
    if (n < NN && q < 4) {
        float4 bv = *(const float4*)(bg2 + q * 4);
        float4 v;
        v.x = tanhf(fmaxf(0.25f * al[q * 4 + 0] + bv.x, 0.f));
        v.y = tanhf(fmaxf(0.25f * al[q * 4 + 1] + bv.y, 0.f));
        v.z = tanhf(fmaxf(0.25f * al[q * 4 + 2] + bv.z, 0.f));
        v.w = tanhf(fmaxf(0.25f * al[q * 4 + 3] + bv.w, 0.f));
        *(float4*)(out + (size_t)n * 16 + q * 4) = v;
    }
}

// ===== aggregate 2 + fused alds2: y gathered as fp16; emits x3h (fp16, stride 32) =====
__global__ __launch_bounds__(256) void k_agg2(const int* __restrict__ rp,
                                              const int* __restrict__ srcs2,
                                              const f16* __restrict__ y,
                                              const float* __restrict__ bias,
                                              const float* __restrict__ U2p,
                                              const float* __restrict__ x3prev,
                                              f16* __restrict__ x3h,
                                              float* __restrict__ alds) {
    __shared__ float sh_inv[4][8];
    int wid = threadIdx.x >> 6, lane = threadIdx.x & 63;
    int n = blockIdx.x * 4 + wid;
    int rpv = (lane <= 8) ? rp[n * RR + lane] : 0;
    int nxt = __shfl(rpv, (lane + 1) & 63);
    if (lane < 8) sh_inv[wid][lane] = 1.f / (float)((nxt - rpv) > 0 ? (nxt - rpv) : 1);
    int q = lane & 7;
    int beg = rp[n * RR], end = rp[n * RR + RR];
    float4 acc = make_float4(0.f, 0.f, 0.f, 0.f);
    int k = beg + (lane >> 3);
    for (; k + 8 < end; k += 16) {
        int key0 = srcs2[k], key1 = srcs2[k + 8];
        int s0 = key0 >> 3, s1 = key1 >> 3;
        int g0 = key0 & 7, g1 = key1 & 7;
        float e0 = sh_inv[wid][g0], e1 = sh_inv[wid][g1];
        float4 v0 = h4tof4(*(const h4*)(y + ((size_t)(g0 >> 1) * NN + s0) * 64 + (g0 & 1) * 32 + q * 4));
        float4 v1 = h4tof4(*(const h4*)(y + ((size_t)(g1 >> 1) * NN + s1) * 64 + (g1 & 1) * 32 + q * 4));
        fmacc(acc, v0, e0);
        fmacc(acc, v1, e1);
    }
    if (k < end) {
        int key0 = srcs2[k];
        int s0 = key0 >> 3;
        int g0 = key0 & 7;
        float4 v0 = h4tof4(*(const h4*)(y + ((size_t)(g0 >> 1) * NN + s0) * 64 + (g0 & 1) * 32 + q * 4));
        fmacc(acc, v0, sh_inv[wid][g0]);
    }
    red4(acc, 8);
    red4(acc, 16);
    red4(acc, 32);
    if (lane < 8) {
        float4 prev = *(const float4*)(x3prev + (size_t)n * 64 + q * 4);
        float4 b = *(const float4*)(bias + q * 4);
        float4 v;
        v.x = fmaxf(prev.x + acc.x + b.x, 0.f);
        v.y = fmaxf(prev.y + acc.y + b.y, 0.f);
        v.z = fmaxf(prev.z + acc.z + b.z, 0.f);
        v.w = fmaxf(prev.w + acc.w + b.w, 0.f);
        h4 hv = {(f16)v.x, (f16)v.y, (f16)v.z, (f16)v.w};
        *(h4*)(x3h + (size_t)n * 32 + q * 4) = hv;
        // fused alds2: al[j] = sum_c x3[n][c] * U2p[c*64+j], c = q*4..q*4+3 per lane
        float al[8];
#pragma unroll
        for (int j = 0; j < 8; j++) {
            al[j] = fmaf(v.x, U2p[(q * 4 + 0) * 64 + j],
                    fmaf(v.y, U2p[(q * 4 + 1) * 64 + j],
                    fmaf(v.z, U2p[(q * 4 + 2) * 64 + j],
                         v.w * U2p[(q * 4 + 3) * 64 + j])));
        }
#pragma unroll
        for (int m = 1; m < 8; m <<= 1) {
#pragma unroll
            for (int j = 0; j < 8; j++) al[j] += __shfl_xor(al[j], m);
        }
        alds[n * 8 + q] = al[q];
    }
}

// ===== fused GAT aggregation; X gathered as fp16 (LDX in f16 elements) =====
template <int F, int LDX = F>
__global__ __launch_bounds__(256) void k_gatx(const int* __restrict__ rp,
                                              const int* __restrict__ srcs2,
                                              const float* __restrict__ alds,
                                              const f16* __restrict__ X,
                                              float* __restrict__ msg) {
    constexpr int G = F / 4;    // lanes per edge-group (16 or 8)
    constexpr int NG = 64 / G;  // groups per wave (4 or 8)
    int wid = threadIdx.x >> 6, lane = threadIdx.x & 63;
    int n = blockIdx.x * 4 + wid;
    if (n >= NN) return;
    int g = lane / G, q = lane % G;
    float4 ald4 = *(const float4*)(alds + n * 8 + 4);
    float4 acc0 = make_float4(0.f, 0.f, 0.f, 0.f);
    float4 acc1 = acc0, acc2 = acc0, acc3 = acc0;
    float4 z = make_float4(0.f, 0.f, 0.f, 0.f);
    if (g == 0) {  // self loop
        float4 a4 = *(const float4*)(alds + n * 8);
        float4 xv = h4tof4(*(const h4*)(X + (size_t)n * LDX + q * 4));
        float p0 = __expf(leaky(a4.x + ald4.x));
        float p1 = __expf(leaky(a4.y + ald4.y));
        float p2 = __expf(leaky(a4.z + ald4.z));
        float p3 = __expf(leaky(a4.w + ald4.w));
        z = make_float4(p0, p1, p2, p3);
        fmacc(acc0, xv, p0);
        fmacc(acc1, xv, p1);
        fmacc(acc2, xv, p2);
        fmacc(acc3, xv, p3);
    }
    int beg = rp[n * RR], end = rp[n * RR + RR];
    int k = beg + g;
    for (; k + NG < end; k += 2 * NG) {
        int s0 = srcs2[k] >> 3, s1 = srcs2[k + NG] >> 3;
        float4 a0 = *(const float4*)(alds + s0 * 8);
        float4 a1 = *(const float4*)(alds + s1 * 8);
        float4 x0 = h4tof4(*(const h4*)(X + (size_t)s0 * LDX + q * 4));
        float4 x1v = h4tof4(*(const h4*)(X + (size_t)s1 * LDX + q * 4));
        float p00 = __expf(leaky(a0.x + ald4.x)), p01 = __expf(leaky(a0.y + ald4.y));
        float p02 = __expf(leaky(a0.z + ald4.z)), p03 = __expf(leaky(a0.w + ald4.w));
        float p10 = __expf(leaky(a1.x + ald4.x)), p11 = __expf(leaky(a1.y + ald4.y));
        float p12 = __expf(leaky(a1.z + ald4.z)), p13 = __expf(leaky(a1.w + ald4.w));
        z.x += p00 + p10;
        z.y += p01 + p11;
        z.z += p02 + p12;
        z.w += p03 + p13;
        fmacc(acc0, x0, p00);
        fmacc(acc1, x0, p01);
        fmacc(acc2, x0, p02);
        fmacc(acc3, x0, p03);
        fmacc(acc0, x1v, p10);
        fmacc(acc1, x1v, p11);
        fmacc(acc2, x1v, p12);
        fmacc(acc3, x1v, p13);
    }
    if (k < end) {
        int s0 = srcs2[k] >> 3;
        float4 a0 = *(const float4*)(alds + s0 * 8);
        float4 x0 = h4tof4(*(const h4*)(X + (size_t)s0 * LDX + q * 4));
        float p00 = __expf(leaky(a0.x + ald4.x)), p01 = __expf(leaky(a0.y + ald4.y));
        float p02 = __expf(leaky(a0.z + ald4.z)), p03 = __expf(leaky(a0.w + ald4.w));
        z.x += p00;
        z.y += p01;
        z.z += p02;
        z.w += p03;
        fmacc(acc0, x0, p00);
        fmacc(acc1, x0, p01);
        fmacc(acc2, x0, p02);
        fmacc(acc3, x0, p03);
    }
#pragma unroll
    for (int m = G; m < 64; m <<= 1) {
        red4(acc0, m);
        red4(acc1, m);
        red4(acc2, m);
        red4(acc3, m);
        red4(z, m);
    }
    if (g == 0) {
        float4 iz = make_float4(1.f / z.x, 1.f / z.y, 1.f / z.z, 1.f / z.w);
        float* mp = msg + (size_t)n * 4 * F + q * 4;
        *(float4*)(mp + 0 * F) = make_float4(acc0.x * iz.x, acc0.y * iz.x, acc0.z * iz.x, acc0.w * iz.x);
        *(float4*)(mp + 1 * F) = make_float4(acc1.x * iz.y, acc1.y * iz.y, acc1.z * iz.y, acc1.w * iz.y);
        *(float4*)(mp + 2 * F) = make_float4(acc2.x * iz.z, acc2.y * iz.z, acc2.z * iz.z, acc2.w * iz.z);
        *(float4*)(mp + 3 * F) = make_float4(acc3.x * iz.w, acc3.y * iz.w, acc3.z * iz.w, acc3.w * iz.w);
    }
}

extern "C" void kernel_launch(void* const* d_in, const int* in_sizes, int n_in,
                              void* d_out, int out_size, void* d_ws, size_t ws_size,
                              hipStream_t stream) {
    const float* x      = (const float*)d_in[0];
    const int*   ei     = (const int*)d_in[1];
    const int*   et     = (const int*)d_in[2];
    const float* basis1 = (const float*)d_in[3];
    const float* comp1  = (const float*)d_in[4];
    const float* root1  = (const float*)d_in[5];
    const float* brg1   = (const float*)d_in[6];
    const float* wg1    = (const float*)d_in[7];
    const float* asrc1  = (const float*)d_in[8];
    const float* adst1  = (const float*)d_in[9];
    const float* bg1    = (const float*)d_in[10];
    const float* basis2 = (const float*)d_in[11];
    const float* comp2  = (const float*)d_in[12];
    const float* root2  = (const float*)d_in[13];
    const float* brg2   = (const float*)d_in[14];
    const float* wg2    = (const float*)d_in[15];
    const float* asrc2  = (const float*)d_in[16];
    const float* adst2  = (const float*)d_in[17];
    const float* bg2    = (const float*)d_in[18];
    const int* src = ei;
    const int* dst = ei + EE;
    float* out = (float*)d_out;

    // ---- int region ----
    int* wsi = (int*)d_ws;
    size_t ioff = 0;
    auto ialloc = [&](size_t n) { int* p = wsi + ioff; ioff += (n + 3) & ~(size_t)3; return p; };
    int* cnt2 = ialloc(SEGS);
    int* rp   = ialloc(SEGS + 1);
    int* bsum = ialloc(2048);
    int* srcs2 = ialloc(EE);
    int* recbuf = ialloc(EE);
    int* cbcur = ialloc(128);
    // ---- float region ----
    float* wsf = (float*)(wsi + ioff);
    size_t total_f = (ws_size - ioff * sizeof(int)) / sizeof(float);
    size_t P_f = (size_t)NN * 320;
    size_t need_f = P_f + (size_t)NN * 128
                  + 40960 + 20480 + 16384 + 8192 + 4096 + 2048
                  + (size_t)NN * 8
                  + 20480 + 8192 + 40960
                  + (size_t)NN * 32 + (size_t)NN * 16 + 64;  // x1h, x3h (fp16)
    if (total_f < need_f) return;  // loud fail: output stays zero
    size_t foff = 0;
    auto falloc = [&](size_t n) { float* p = wsf + foff; foff += (n + 3) & ~(size_t)3; return p; };
    float* P      = falloc(P_f);
    float* x2     = falloc((size_t)NN * 128);
    float* Wcat2e = falloc(40960);           // [128][320]: root2(pad) | W_r pairs
    float* Wb1    = falloc(20480);           // [320][64]: basis1 rows | root1 rows
    float* wg1r   = falloc(16384);
    float* Wstk   = falloc(8192);
    float* U1p    = falloc(4096);
    float* U2p    = falloc(2048);
    float* alds   = falloc((size_t)NN * 8);
    short* Wb1pk  = (short*)falloc(20480);   // 40 pairs x 1024 shorts
    short* wg1rpk = (short*)falloc(8192);    // 16 pairs
    short* Wcatpk = (short*)falloc(40960);   // 80 pairs (5 panels x 16)
    f16* x1h      = (f16*)falloc((size_t)NN * 32);  // [n][64] fp16
    f16* x3h      = (f16*)falloc((size_t)NN * 16);  // [n][32] fp16
    float* Ubuf = P;                  // L1 basis-gather output [n][320]
    float* x1   = x2 + (size_t)NN * 64;  // dead before msg1-gemm overwrites x2 region
    float* msg1 = P;                  // [n][4][64] (U dead after u-gemm)
    float* x3   = P;                  // fp32 root-panel out (read as prev by agg2)
    f16* ybuf3h = (f16*)(P + (size_t)NN * 64);  // L3 rel panels [4][n][64] fp16
    float* msg2 = P + (size_t)NN * 64;   // [n][4][32] (ybuf3h dead after agg2)

    const int EB = (EE + 255) / 256;
    const int NB4 = (NN + 3) / 4;    // NN % 4 == 0 -> exact
    const int NB32 = (NN + 31) / 32; // 1563 (skinny matvec blocks, 32 nodes each)

    // ---- CSR build (two-phase binned fill: dense writes, no line amplification) ----
    hipMemsetAsync(cnt2, 0, SEGS * sizeof(int), stream);
    k_count2<<<EB, 256, 0, stream>>>(dst, et, cnt2);
    k_scanA<<<NBLK, 256, 0, stream>>>(cnt2, rp, bsum);
    k_scanB<<<1, 256, 0, stream>>>(bsum);
    k_scanC<<<NBLK, 256, 0, stream>>>(rp, bsum);
    k_initcb<<<1, 128, 0, stream>>>(rp, cbcur);
    k_fillA<<<EB4, 256, 0, stream>>>(src, dst, et, cbcur, recbuf);
    k_fillB<<<NBUK, 256, 0, stream>>>(rp, recbuf, srcs2);
    k_prep<<<(92160 + 255) / 256, 256, 0, stream>>>(
        wg1, wg2, root1, root2, basis1, basis2, comp2, asrc1, adst1, asrc2, adst2,
        Wcat2e, wg1r, Wstk, U1p, U2p, Wb1);
    k_pack<<<34, 256, 0, stream>>>(Wb1, wg1r, Wcat2e, Wb1pk, wg1rpk, Wcatpk);

    // ---- layer 1: RGCN(64->64)+relu via basis-space gather + one K=320 MFMA GEMM ----
    k_gagg1<<<NB4, 256, 0, stream>>>(rp, srcs2, comp1, x, Ubuf);
    k_mfma<320, 64, 2><<<dim3(NTW, 1), 256, 0, stream>>>(Ubuf, 320, 0, Wb1pk, 0,
                                                         x1, 64, 0, brg1, 0);

    // ---- layer 2: GAT(64 -> 4x32 concat), fp16 gather of x1 ----
    k_alds1<<<NB32, 256, 0, stream>>>(x1, U1p, alds, x1h);
    k_gatx<64, 64><<<NB4, 256, 0, stream>>>(rp, srcs2, alds, x1h, msg1);
    k_mfma<64, 32, 0><<<dim3(NTW, 4), 256, 0, stream>>>(msg1, 256, 64, wg1rpk, 4096,
                                                        x2, 128, 32, bg1, 32);

    // ---- layer 3: RGCN(128->32)+relu; root fp32 + 4 rel panels fp16 via MFMA ----
    k_mfma<128, 64, 0, 0><<<dim3(NTW, 1), 256, 0, stream>>>(x2, 128, 0, Wcatpk, 0,
                                                            P, 64, 0, nullptr, 0);
    k_mfma<128, 64, 0, 1><<<dim3(NTW, 4), 256, 0, stream>>>(x2, 128, 0, Wcatpk + 16384, 16384,
                                                            (float*)ybuf3h, 64, (size_t)NN * 64,
                                                            nullptr, 0);
    k_agg2<<<NB4, 256, 0, stream>>>(rp, srcs2, ybuf3h, brg2, U2p, x3, x3h, alds);

    // ---- layer 4: GAT(32 -> 4x16, mean heads) + relu + tanh, fp16 gather of x3 ----
    k_gatx<32, 32><<<NB4, 256, 0, stream>>>(rp, srcs2, alds, x3h, msg2);
    k_final<<<NB32, 256, 0, stream>>>(msg2, Wstk, bg2, out);
}